// Round 5
// baseline (1921.471 us; speedup 1.0000x reference)
//
#include <hip/hip_runtime.h>

#define K256 __launch_bounds__(256)

constexpr int B = 128;
constexpr int NM = 100000, EM = 400000;
constexpr int NP = 200000, EP = 3200000;
constexpr int DM = 78, DPK = 54, DP2 = 108;

// ---------- CSR build ----------
__global__ void K256 k_count4(const int4* __restrict__ dst, int* __restrict__ deg, int E4) {
  int e = blockIdx.x * 256 + threadIdx.x;
  if (e < E4) {
    int4 v = dst[e];
    atomicAdd(&deg[v.x], 1);
    atomicAdd(&deg[v.y], 1);
    atomicAdd(&deg[v.z], 1);
    atomicAdd(&deg[v.w], 1);
  }
}

__global__ void k_scan1(const int* __restrict__ deg, int* __restrict__ incl,
                        int* __restrict__ bsum, int N) {
  __shared__ int s[1024];
  int i = blockIdx.x * 1024 + threadIdx.x;
  int v = (i < N) ? deg[i] : 0;
  s[threadIdx.x] = v;
  __syncthreads();
  for (int off = 1; off < 1024; off <<= 1) {
    int t = (threadIdx.x >= off) ? s[threadIdx.x - off] : 0;
    __syncthreads();
    s[threadIdx.x] += t;
    __syncthreads();
  }
  if (i < N) incl[i] = s[threadIdx.x];
  if (threadIdx.x == 1023) bsum[blockIdx.x] = s[1023];
}

__global__ void k_scan2(int* __restrict__ bsum, int nb) {
  __shared__ int s[256];
  int v = (threadIdx.x < (unsigned)nb) ? bsum[threadIdx.x] : 0;
  s[threadIdx.x] = v;
  __syncthreads();
  for (int off = 1; off < 256; off <<= 1) {
    int t = (threadIdx.x >= off) ? s[threadIdx.x - off] : 0;
    __syncthreads();
    s[threadIdx.x] += t;
    __syncthreads();
  }
  if (threadIdx.x < (unsigned)nb) bsum[threadIdx.x] = s[threadIdx.x] - v;  // exclusive
}

__global__ void K256 k_scan3(const int* __restrict__ incl, const int* __restrict__ deg,
                             const int* __restrict__ bsum, int* __restrict__ starts, int N) {
  int i = blockIdx.x * 256 + threadIdx.x;
  if (i < N) starts[i] = incl[i] - deg[i] + bsum[i >> 10];
}

template <int SH>
__global__ void K256 k_bcur(const int* __restrict__ starts, int* __restrict__ bcur, int N) {
  int b = blockIdx.x * 256 + threadIdx.x;
  int NB = (N + (1 << SH) - 1) >> SH;
  if (b < NB) bcur[b] = starts[b << SH];
}

// Pass A: bucket-grouped edge binning (counting-sort per 4096-edge chunk).
template <int SH>
__global__ void K256 k_bin(const int* __restrict__ src, const int* __restrict__ dst,
                           int* __restrict__ bcur, int2* __restrict__ binned, int E) {
  __shared__ int lh[512];
  __shared__ int gbase[512];
  int c0 = blockIdx.x * 4096;
  int tid = threadIdx.x;
  for (int t = tid; t < 512; t += 256) lh[t] = 0;
  __syncthreads();
  int r[16], dcache[16];
#pragma unroll
  for (int k = 0; k < 16; k++) {
    int e = c0 + k * 256 + tid;
    if (e < E) {
      int d = dst[e];
      dcache[k] = d;
      r[k] = atomicAdd(&lh[d >> SH], 1);
    }
  }
  __syncthreads();
  for (int b = tid; b < 512; b += 256) {
    int c = lh[b];
    gbase[b] = c ? atomicAdd(&bcur[b], c) : 0;
  }
  __syncthreads();
#pragma unroll
  for (int k = 0; k < 16; k++) {
    int e = c0 + k * 256 + tid;
    if (e < E) {
      int d = dcache[k];
      binned[gbase[d >> SH] + r[k]] = make_int2(src[e], d);
    }
  }
}

// Pass B: per-bucket CSR fill; node cursors in LDS.
template <int SH>
__global__ void K256 k_fill2(const int2* __restrict__ binned, const int* __restrict__ starts,
                             int* __restrict__ csr, int N, int E) {
  __shared__ int lcur[1 << SH];
  int b = blockIdx.x;
  int base = b << SH;
  int nn = min(N - base, 1 << SH);
  int tid = threadIdx.x;
  for (int t = tid; t < nn; t += 256) lcur[t] = starts[base + t];
  __syncthreads();
  int r0 = starts[base];
  int r1 = (base + (1 << SH) >= N) ? E : starts[base + (1 << SH)];
  for (int e = r0 + tid; e < r1; e += 256) {
    int2 sd = binned[e];
    int p = atomicAdd(&lcur[sd.y - base], 1);
    csr[p] = sd.x;
  }
}

// ---------- batch segment starts (batch is sorted) ----------
__global__ void K256 k_bstart(const int* __restrict__ batch, int* __restrict__ bstart, int N) {
  int i = blockIdx.x * 256 + threadIdx.x;
  if (i < N) {
    int b = batch[i];
    int pb = (i == 0) ? -1 : batch[i - 1];
    for (int bb = pb + 1; bb <= b; bb++) bstart[bb] = i;
    if (i == N - 1)
      for (int bb = b + 1; bb <= B; bb++) bstart[bb] = N;
  }
}

// ---------- small transpose ----------
__global__ void K256 k_trans(const float* __restrict__ in, float* __restrict__ out, int R, int C) {
  int i = blockIdx.x * 256 + threadIdx.x;
  if (i < R * C) {
    int r = i / C, c = i - r * C;
    out[c * R + r] = in[i];
  }
}

// ---------- gather aggregation: wave per node, float2 lanes ----------
template <int D, bool MEAN>
__global__ void K256 k_gatherv(const float* __restrict__ x, const int* __restrict__ starts,
                               const int* __restrict__ deg, const int* __restrict__ csr,
                               float* __restrict__ out, int N, int ostride) {
  constexpr int NF2 = D / 2;
  int wid = (blockIdx.x * 256 + threadIdx.x) >> 6;
  int lane = threadIdx.x & 63;
  if (wid >= N) return;
  int s = starts[wid], d = deg[wid];
  const int* cp = csr + s;
  float ax = 0.f, ay = 0.f;
  if constexpr (NF2 <= 32) {
    int half = lane >> 5, sl = lane & 31;
    bool act = sl < NF2;
    for (int j = 0; j < d; j += 2) {
      int e = j + half;
      if (e < d && act) {
        const float2* row = (const float2*)(x + (size_t)cp[e] * D);
        float2 v = row[sl];
        ax += v.x;
        ay += v.y;
      }
    }
    ax += __shfl_xor(ax, 32, 64);
    ay += __shfl_xor(ay, 32, 64);
    if (half == 0 && act) {
      float inv = MEAN ? 1.f / fmaxf((float)d, 1.f) : 1.f;
      float2* op = (float2*)(out + (size_t)wid * ostride);
      float2 w;
      w.x = ax * inv;
      w.y = ay * inv;
      op[sl] = w;
    }
  } else {
    bool act = lane < NF2;
    for (int j = 0; j < d; j++) {
      if (act) {
        const float2* row = (const float2*)(x + (size_t)cp[j] * D);
        float2 v = row[lane];
        ax += v.x;
        ay += v.y;
      }
    }
    if (act) {
      float inv = MEAN ? 1.f / fmaxf((float)d, 1.f) : 1.f;
      float2* op = (float2*)(out + (size_t)wid * ostride);
      float2 w;
      w.x = ax * inv;
      w.y = ay * inv;
      op[lane] = w;
    }
  }
}

// ---------- segmented pooling ----------
template <int D, int NPB, bool ACCUM>
__global__ void K256 k_pool_seg(const float* __restrict__ x, const int* __restrict__ bstart,
                                float* __restrict__ pooled, float coef) {
  __shared__ float sp[D * NPB];
  int b = blockIdx.x, tid = threadIdx.x;
  int r0 = bstart[b], r1 = bstart[b + 1];
  if (tid < D * NPB) {
    int ioff = tid / D, f = tid - ioff * D;
    float acc = 0.f;
    for (int i = r0 + ioff; i < r1; i += NPB) acc += x[(size_t)i * D + f];
    sp[tid] = acc;
  }
  __syncthreads();
  if (tid < D) {
    float s = 0.f;
#pragma unroll
    for (int g = 0; g < NPB; g++) s += sp[g * D + tid];
    s *= coef;
    if (ACCUM)
      pooled[b * D + tid] += s;
    else
      pooled[b * D + tid] = s;
  }
}

// ---------- SAGE conv1: LDS-staged tile, lane=node, wave-uniform output half ----------
// block: 256 thr, 128 nodes; waves (0,1)->nodes 0..63 (halves 0,1), (2,3)->nodes 64..127
__global__ void __launch_bounds__(256, 2) k_sage1_lds(
    const float* __restrict__ x, const float* __restrict__ agg,
    const float* __restrict__ WlT, const float* __restrict__ bl,
    const float* __restrict__ WrT, float* __restrict__ out, int N) {
  __shared__ float sx[128 * DPK];
  __shared__ float sa[128 * DPK];
  int base = blockIdx.x * 128;
  int nn = min(N - base, 128);
  int tid = threadIdx.x;
  int cnt2 = nn * (DPK / 2);
  const float2* xg = (const float2*)(x + (size_t)base * DPK);
  const float2* ag = (const float2*)(agg + (size_t)base * DPK);
  for (int t = tid; t < cnt2; t += 256) {
    ((float2*)sx)[t] = xg[t];
    ((float2*)sa)[t] = ag[t];
  }
  __syncthreads();
  int w = tid >> 6, lane = tid & 63;
  int h = w & 1;                     // wave-uniform output half
  int node = (w >> 1) * 64 + lane;   // 0..127
  if (node >= nn) return;
  int obase = h * 27;
  float acc[27];
#pragma unroll
  for (int o = 0; o < 27; o++) acc[o] = bl[obase + o];
  const float* rx = sx + node * DPK;
  const float* ra = sa + node * DPK;
#pragma unroll 2
  for (int k = 0; k < DPK; k++) {
    float xv = rx[k], av = ra[k];
    const float* wl = WlT + k * DPK + obase;
    const float* wr = WrT + k * DPK + obase;
#pragma unroll
    for (int o = 0; o < 27; o++) acc[o] += av * wl[o] + xv * wr[o];
  }
  float* op = out + (size_t)(base + node) * DPK + obase;
#pragma unroll
  for (int o = 0; o < 27; o++) op[o] = fmaxf(acc[o], 0.f);
}

// ---------- conv2 + segment-mean pool: LDS-staged tiles within one segment slice ----------
template <int SPLIT>
__global__ void __launch_bounds__(256, 2) k_sage2_lds(
    const float* __restrict__ xt1, const float* __restrict__ agg,
    const float* __restrict__ WlT, const float* __restrict__ bl,
    const float* __restrict__ WrT, const int* __restrict__ bstart,
    float* __restrict__ pooled) {
  constexpr int OH = DP2 / 2;  // 54 outputs per wave-half
  __shared__ float sx[128 * DPK];
  __shared__ float sa[128 * DPK];
  int b = blockIdx.x / SPLIT;
  int sidx = blockIdx.x - b * SPLIT;
  int tid = threadIdx.x;
  int w = tid >> 6, lane = tid & 63;
  int h = w & 1;
  int lnode = (w >> 1) * 64 + lane;
  int obase = h * OH;
  int r0 = bstart[b], r1 = bstart[b + 1];
  int len = r1 - r0;
  int per = (len + SPLIT - 1) / SPLIT;
  int s0 = r0 + sidx * per;
  int s1 = min(r1, s0 + per);
  float pool[OH];
#pragma unroll
  for (int o = 0; o < OH; o++) pool[o] = 0.f;
  for (int tb = s0; tb < s1; tb += 128) {
    int nn = min(s1 - tb, 128);
    int cnt2 = nn * (DPK / 2);
    const float2* xg = (const float2*)(xt1 + (size_t)tb * DPK);
    const float2* ag = (const float2*)(agg + (size_t)tb * DPK);
    __syncthreads();  // protect LDS from previous iteration's readers
    for (int t = tid; t < cnt2; t += 256) {
      ((float2*)sx)[t] = xg[t];
      ((float2*)sa)[t] = ag[t];
    }
    __syncthreads();
    if (lnode < nn) {
      float acc[OH];
#pragma unroll
      for (int o = 0; o < OH; o++) acc[o] = bl[obase + o];
      const float* rx = sx + lnode * DPK;
      const float* ra = sa + lnode * DPK;
#pragma unroll 2
      for (int k = 0; k < DPK; k++) {
        float xv = rx[k], av = ra[k];
        const float* wl = WlT + k * DP2 + obase;
        const float* wr = WrT + k * DP2 + obase;
#pragma unroll
        for (int o = 0; o < OH; o++) acc[o] += av * wl[o] + xv * wr[o];
      }
#pragma unroll
      for (int o = 0; o < OH; o++) pool[o] += fmaxf(acc[o], 0.f);
    }
  }
#pragma unroll
  for (int o = 0; o < OH; o++) {
#pragma unroll
    for (int off = 1; off < 64; off <<= 1) pool[o] += __shfl_xor(pool[o], off, 64);
  }
  if (lane == 0) {
    float* pb = pooled + b * DP2 + obase;
#pragma unroll
    for (int o = 0; o < OH; o++)
      if (pool[o] != 0.f) atomicAdd(&pb[o], pool[o]);
  }
}

// ---------- branch head MLP ----------
template <int DIN, int DOUT>
__global__ void K256 k_head(const float* __restrict__ pooled, const int* __restrict__ bstart,
                            const float* __restrict__ W1, const float* __restrict__ b1,
                            const float* __restrict__ W2, const float* __restrict__ b2,
                            float* __restrict__ outv) {
  __shared__ float sx[DIN];
  __shared__ float sh[256];
  int b = blockIdx.x, tid = threadIdx.x;
  float inv = 1.f / fmaxf((float)(bstart[b + 1] - bstart[b]), 1.f);
  for (int f = tid; f < DIN; f += 256) sx[f] = pooled[b * DIN + f] * inv;
  __syncthreads();
  float acc = b1[tid];
#pragma unroll 2
  for (int k = 0; k < DIN; k++) acc += sx[k] * W1[tid * DIN + k];
  sh[tid] = fmaxf(acc, 0.f);
  __syncthreads();
  if (tid < DOUT) {
    float a = b2[tid];
#pragma unroll 4
    for (int k = 0; k < 256; k++) a += sh[k] * W2[tid * 256 + k];
    outv[b * DOUT + tid] = a;
  }
}

// ---------- final MLP ----------
__global__ void K256 k_final(const float* __restrict__ molv, const float* __restrict__ prov,
                             const float* __restrict__ W1, const float* __restrict__ b1,
                             const float* __restrict__ W2, const float* __restrict__ b2,
                             const float* __restrict__ W3, const float* __restrict__ b3,
                             float* __restrict__ out) {
  __shared__ float sx[256];
  __shared__ float sh1[1024];
  __shared__ float sh2[512];
  __shared__ float red[4];
  int b = blockIdx.x, tid = threadIdx.x;
  sx[tid] = (tid < 112) ? molv[b * 112 + tid] : prov[b * 144 + (tid - 112)];
  __syncthreads();
  for (int o = tid; o < 1024; o += 256) {
    float a = b1[o];
#pragma unroll 4
    for (int k = 0; k < 256; k++) a += sx[k] * W1[o * 256 + k];
    sh1[o] = fmaxf(a, 0.f);
  }
  __syncthreads();
  for (int o = tid; o < 512; o += 256) {
    float a = b2[o];
#pragma unroll 4
    for (int k = 0; k < 1024; k++) a += sh1[k] * W2[o * 1024 + k];
    sh2[o] = fmaxf(a, 0.f);
  }
  __syncthreads();
  float a = 0.f;
  for (int k = tid; k < 512; k += 256) a += sh2[k] * W3[k];
  for (int off = 32; off > 0; off >>= 1) a += __shfl_down(a, off, 64);
  if ((tid & 63) == 0) red[tid >> 6] = a;
  __syncthreads();
  if (tid == 0) out[b] = red[0] + red[1] + red[2] + red[3] + b3[0];
}

__global__ void k_report(float* out, float v, int n) {
  int i = blockIdx.x * 256 + threadIdx.x;
  if (i < n) out[i] = v;
}

extern "C" void kernel_launch(void* const* d_in, const int* in_sizes, int n_in,
                              void* d_out, int out_size, void* d_ws, size_t ws_size,
                              hipStream_t stream) {
  (void)in_sizes; (void)n_in;
  const float* mol_x = (const float*)d_in[0];
  const int* m_ei = (const int*)d_in[1];
  const int* m_batch = (const int*)d_in[2];
  const float* pro_x = (const float*)d_in[3];
  const int* p_ei = (const int*)d_in[4];
  const int* p_batch = (const int*)d_in[5];
  const float* mol_W1 = (const float*)d_in[6];
  const float* mol_b1 = (const float*)d_in[7];
  const float* mol_W2 = (const float*)d_in[8];
  const float* mol_b2 = (const float*)d_in[9];
  const float* c1_Wl = (const float*)d_in[10];
  const float* c1_bl = (const float*)d_in[11];
  const float* c1_Wr = (const float*)d_in[12];
  const float* c2_Wl = (const float*)d_in[13];
  const float* c2_bl = (const float*)d_in[14];
  const float* c2_Wr = (const float*)d_in[15];
  const float* pro_W1 = (const float*)d_in[16];
  const float* pro_b1 = (const float*)d_in[17];
  const float* pro_W2 = (const float*)d_in[18];
  const float* pro_b2 = (const float*)d_in[19];
  const float* fc1_W = (const float*)d_in[20];
  const float* fc1_b = (const float*)d_in[21];
  const float* fc2_W = (const float*)d_in[22];
  const float* fc2_b = (const float*)d_in[23];
  const float* out_W = (const float*)d_in[24];
  const float* out_b = (const float*)d_in[25];
  float* out = (float*)d_out;
  char* ws = (char*)d_ws;

  const int* m_row = m_ei;       // dst
  const int* m_col = m_ei + EM;  // src
  const int* p_e0 = p_ei;        // src
  const int* p_e1 = p_ei + EP;   // dst

  auto al = [](size_t x) { return (x + 255) & ~(size_t)255; };

  size_t o = 0;
  size_t o_pdeg = o;   o += al((size_t)NP * 4);
  size_t o_pincl = o;  o += al((size_t)NP * 4);
  size_t o_pstart = o; o += al((size_t)NP * 4);
  size_t o_pbsum = o;  o += al(1024);
  size_t o_pcsr = o;   o += al((size_t)EP * 4);
  size_t o_agg = o;    o += al((size_t)NP * DPK * 4);  // also pro binned
  size_t o_xt1 = o;    o += al((size_t)NP * DPK * 4);
  size_t pro_end = o;

  o = 0;
  size_t o_mdeg = o;   o += al((size_t)NM * 4);
  size_t o_mincl = o;  o += al((size_t)NM * 4);
  size_t o_mstart = o; o += al((size_t)NM * 4);
  size_t o_mbsum = o;  o += al(1024);
  size_t o_mcsr = o;   o += al((size_t)EM * 4);
  size_t o_hA = o;     o += al((size_t)NM * DM * 4);  // also mol binned
  size_t o_hB = o;     o += al((size_t)NM * DM * 4);
  size_t mol_end = o;

  size_t tail = al(pro_end > mol_end ? pro_end : mol_end);
  size_t o_poolM = tail; tail += al((size_t)B * DM * 4);
  size_t o_poolP = tail; tail += al((size_t)B * DP2 * 4);
  size_t o_molv = tail;  tail += al((size_t)B * 112 * 4);
  size_t o_prov = tail;  tail += al((size_t)B * 144 * 4);
  size_t o_mbs = tail;   tail += al((size_t)(B + 1) * 4);
  size_t o_pbs = tail;   tail += al((size_t)(B + 1) * 4);
  size_t o_w1l = tail;   tail += al((size_t)DPK * DPK * 4);
  size_t o_w1r = tail;   tail += al((size_t)DPK * DPK * 4);
  size_t o_w2l = tail;   tail += al((size_t)DPK * DP2 * 4);
  size_t o_w2r = tail;   tail += al((size_t)DPK * DP2 * 4);
  size_t o_mbc = tail;   tail += al(512 * 4);
  size_t o_pbc = tail;   tail += al(512 * 4);

  if (ws_size < tail) {
    k_report<<<1, 256, 0, stream>>>(out, (float)(ws_size >> 20), out_size);
    return;
  }

  int* mdeg = (int*)(ws + o_mdeg);
  int* mincl = (int*)(ws + o_mincl);
  int* mstart = (int*)(ws + o_mstart);
  int* mbsum = (int*)(ws + o_mbsum);
  int* mcsr = (int*)(ws + o_mcsr);
  float* hA = (float*)(ws + o_hA);
  float* hB = (float*)(ws + o_hB);
  int* pdeg = (int*)(ws + o_pdeg);
  int* pincl = (int*)(ws + o_pincl);
  int* pstart = (int*)(ws + o_pstart);
  int* pbsum = (int*)(ws + o_pbsum);
  int* pcsr = (int*)(ws + o_pcsr);
  float* agg = (float*)(ws + o_agg);
  float* xt1 = (float*)(ws + o_xt1);
  float* poolM = (float*)(ws + o_poolM);
  float* poolP = (float*)(ws + o_poolP);
  float* molv = (float*)(ws + o_molv);
  float* prov = (float*)(ws + o_prov);
  int* mbs = (int*)(ws + o_mbs);
  int* pbs = (int*)(ws + o_pbs);
  float* w1l = (float*)(ws + o_w1l);
  float* w1r = (float*)(ws + o_w1r);
  float* w2l = (float*)(ws + o_w2l);
  float* w2r = (float*)(ws + o_w2r);
  int* mbc = (int*)(ws + o_mbc);
  int* pbc = (int*)(ws + o_pbc);
  int2* mbinned = (int2*)hA;
  int2* pbinned = (int2*)agg;

  // weight transposes (tiny)
  k_trans<<<(DPK * DPK + 255) / 256, 256, 0, stream>>>(c1_Wl, w1l, DPK, DPK);
  k_trans<<<(DPK * DPK + 255) / 256, 256, 0, stream>>>(c1_Wr, w1r, DPK, DPK);
  k_trans<<<(DP2 * DPK + 255) / 256, 256, 0, stream>>>(c2_Wl, w2l, DP2, DPK);
  k_trans<<<(DP2 * DPK + 255) / 256, 256, 0, stream>>>(c2_Wr, w2r, DP2, DPK);

  // ===== MOL branch =====
  constexpr int SHM = 8;
  constexpr int NBM = (NM + (1 << SHM) - 1) >> SHM;
  hipMemsetAsync(mdeg, 0, (size_t)NM * 4, stream);
  k_count4<<<(EM / 4 + 255) / 256, 256, 0, stream>>>((const int4*)m_row, mdeg, EM / 4);
  int nb_m = (NM + 1023) / 1024;
  k_scan1<<<nb_m, 1024, 0, stream>>>(mdeg, mincl, mbsum, NM);
  k_scan2<<<1, 256, 0, stream>>>(mbsum, nb_m);
  k_scan3<<<(NM + 255) / 256, 256, 0, stream>>>(mincl, mdeg, mbsum, mstart, NM);
  k_bcur<SHM><<<(NBM + 255) / 256, 256, 0, stream>>>(mstart, mbc, NM);
  k_bin<SHM><<<(EM + 4095) / 4096, 256, 0, stream>>>(m_col, m_row, mbc, mbinned, EM);
  k_fill2<SHM><<<NBM, 256, 0, stream>>>(mbinned, mstart, mcsr, NM, EM);
  k_bstart<<<(NM + 255) / 256, 256, 0, stream>>>(m_batch, mbs, NM);

  int gb_m = (NM * 64 + 255) / 256;
  k_pool_seg<DM, 3, false><<<B, 256, 0, stream>>>(mol_x, mbs, poolM, 0.05f);
  k_gatherv<DM, false><<<gb_m, 256, 0, stream>>>(mol_x, mstart, mdeg, mcsr, hA, NM, DM);
  k_pool_seg<DM, 3, true><<<B, 256, 0, stream>>>(hA, mbs, poolM, 0.2375f);
  k_gatherv<DM, false><<<gb_m, 256, 0, stream>>>(hA, mstart, mdeg, mcsr, hB, NM, DM);
  k_pool_seg<DM, 3, true><<<B, 256, 0, stream>>>(hB, mbs, poolM, 0.2375f);
  k_gatherv<DM, false><<<gb_m, 256, 0, stream>>>(hB, mstart, mdeg, mcsr, hA, NM, DM);
  k_pool_seg<DM, 3, true><<<B, 256, 0, stream>>>(hA, mbs, poolM, 0.2375f);
  k_gatherv<DM, false><<<gb_m, 256, 0, stream>>>(hA, mstart, mdeg, mcsr, hB, NM, DM);
  k_pool_seg<DM, 3, true><<<B, 256, 0, stream>>>(hB, mbs, poolM, 0.2375f);
  k_head<DM, 112><<<B, 256, 0, stream>>>(poolM, mbs, mol_W1, mol_b1, mol_W2, mol_b2, molv);

  // ===== PRO branch =====
  constexpr int SHP = 9;
  constexpr int NBP = (NP + (1 << SHP) - 1) >> SHP;
  hipMemsetAsync(pdeg, 0, (size_t)NP * 4, stream);
  hipMemsetAsync(poolP, 0, (size_t)B * DP2 * 4, stream);
  k_count4<<<(EP / 4 + 255) / 256, 256, 0, stream>>>((const int4*)p_e1, pdeg, EP / 4);
  int nb_p = (NP + 1023) / 1024;
  k_scan1<<<nb_p, 1024, 0, stream>>>(pdeg, pincl, pbsum, NP);
  k_scan2<<<1, 256, 0, stream>>>(pbsum, nb_p);
  k_scan3<<<(NP + 255) / 256, 256, 0, stream>>>(pincl, pdeg, pbsum, pstart, NP);
  k_bcur<SHP><<<(NBP + 255) / 256, 256, 0, stream>>>(pstart, pbc, NP);
  k_bin<SHP><<<(EP + 4095) / 4096, 256, 0, stream>>>(p_e0, p_e1, pbc, pbinned, EP);
  k_fill2<SHP><<<NBP, 256, 0, stream>>>(pbinned, pstart, pcsr, NP, EP);
  k_bstart<<<(NP + 255) / 256, 256, 0, stream>>>(p_batch, pbs, NP);

  int gb_p = (NP * 64 + 255) / 256;
  k_gatherv<DPK, true><<<gb_p, 256, 0, stream>>>(pro_x, pstart, pdeg, pcsr, agg, NP, DPK);
  k_sage1_lds<<<(NP + 127) / 128, 256, 0, stream>>>(pro_x, agg, w1l, c1_bl, w1r, xt1, NP);
  k_gatherv<DPK, true><<<gb_p, 256, 0, stream>>>(xt1, pstart, pdeg, pcsr, agg, NP, DPK);
  k_sage2_lds<4><<<B * 4, 256, 0, stream>>>(xt1, agg, w2l, c2_bl, w2r, pbs, poolP);
  k_head<DP2, 144><<<B, 256, 0, stream>>>(poolP, pbs, pro_W1, pro_b1, pro_W2, pro_b2, prov);

  k_final<<<B, 256, 0, stream>>>(molv, prov, fc1_W, fc1_b, fc2_W, fc2_b, out_W, out_b, out);
}

// Round 6
// 1534.708 us; speedup vs baseline: 1.2520x; 1.2520x over previous
//
#include <hip/hip_runtime.h>

#define K256 __launch_bounds__(256)

constexpr int B = 128;
constexpr int NM = 100000, EM = 400000;
constexpr int NP = 200000, EP = 3200000;
constexpr int DM = 78, DPK = 54, DP2 = 108;

// ---------- CSR build ----------
__global__ void K256 k_count4(const int4* __restrict__ dst, int* __restrict__ deg, int E4) {
  int e = blockIdx.x * 256 + threadIdx.x;
  if (e < E4) {
    int4 v = dst[e];
    atomicAdd(&deg[v.x], 1);
    atomicAdd(&deg[v.y], 1);
    atomicAdd(&deg[v.z], 1);
    atomicAdd(&deg[v.w], 1);
  }
}

__global__ void k_scan1(const int* __restrict__ deg, int* __restrict__ incl,
                        int* __restrict__ bsum, int N) {
  __shared__ int s[1024];
  int i = blockIdx.x * 1024 + threadIdx.x;
  int v = (i < N) ? deg[i] : 0;
  s[threadIdx.x] = v;
  __syncthreads();
  for (int off = 1; off < 1024; off <<= 1) {
    int t = (threadIdx.x >= off) ? s[threadIdx.x - off] : 0;
    __syncthreads();
    s[threadIdx.x] += t;
    __syncthreads();
  }
  if (i < N) incl[i] = s[threadIdx.x];
  if (threadIdx.x == 1023) bsum[blockIdx.x] = s[1023];
}

__global__ void k_scan2(int* __restrict__ bsum, int nb) {
  __shared__ int s[256];
  int v = (threadIdx.x < (unsigned)nb) ? bsum[threadIdx.x] : 0;
  s[threadIdx.x] = v;
  __syncthreads();
  for (int off = 1; off < 256; off <<= 1) {
    int t = (threadIdx.x >= off) ? s[threadIdx.x - off] : 0;
    __syncthreads();
    s[threadIdx.x] += t;
    __syncthreads();
  }
  if (threadIdx.x < (unsigned)nb) bsum[threadIdx.x] = s[threadIdx.x] - v;  // exclusive
}

__global__ void K256 k_scan3(const int* __restrict__ incl, const int* __restrict__ deg,
                             const int* __restrict__ bsum, int* __restrict__ starts, int N) {
  int i = blockIdx.x * 256 + threadIdx.x;
  if (i < N) starts[i] = incl[i] - deg[i] + bsum[i >> 10];
}

template <int SH>
__global__ void K256 k_bcur(const int* __restrict__ starts, int* __restrict__ bcur, int N) {
  int b = blockIdx.x * 256 + threadIdx.x;
  int NB = (N + (1 << SH) - 1) >> SH;
  if (b < NB) bcur[b] = starts[b << SH];
}

// Pass A: bucket-grouped edge binning (counting-sort per 4096-edge chunk).
template <int SH>
__global__ void K256 k_bin(const int* __restrict__ src, const int* __restrict__ dst,
                           int* __restrict__ bcur, int2* __restrict__ binned, int E) {
  __shared__ int lh[512];
  __shared__ int gbase[512];
  int c0 = blockIdx.x * 4096;
  int tid = threadIdx.x;
  for (int t = tid; t < 512; t += 256) lh[t] = 0;
  __syncthreads();
  int r[16], dcache[16];
#pragma unroll
  for (int k = 0; k < 16; k++) {
    int e = c0 + k * 256 + tid;
    if (e < E) {
      int d = dst[e];
      dcache[k] = d;
      r[k] = atomicAdd(&lh[d >> SH], 1);
    }
  }
  __syncthreads();
  for (int b = tid; b < 512; b += 256) {
    int c = lh[b];
    gbase[b] = c ? atomicAdd(&bcur[b], c) : 0;
  }
  __syncthreads();
#pragma unroll
  for (int k = 0; k < 16; k++) {
    int e = c0 + k * 256 + tid;
    if (e < E) {
      int d = dcache[k];
      binned[gbase[d >> SH] + r[k]] = make_int2(src[e], d);
    }
  }
}

// Pass B: per-bucket CSR fill; node cursors in LDS.
template <int SH>
__global__ void K256 k_fill2(const int2* __restrict__ binned, const int* __restrict__ starts,
                             int* __restrict__ csr, int N, int E) {
  __shared__ int lcur[1 << SH];
  int b = blockIdx.x;
  int base = b << SH;
  int nn = min(N - base, 1 << SH);
  int tid = threadIdx.x;
  for (int t = tid; t < nn; t += 256) lcur[t] = starts[base + t];
  __syncthreads();
  int r0 = starts[base];
  int r1 = (base + (1 << SH) >= N) ? E : starts[base + (1 << SH)];
  for (int e = r0 + tid; e < r1; e += 256) {
    int2 sd = binned[e];
    int p = atomicAdd(&lcur[sd.y - base], 1);
    csr[p] = sd.x;
  }
}

// ---------- batch segment starts (batch is sorted) ----------
__global__ void K256 k_bstart(const int* __restrict__ batch, int* __restrict__ bstart, int N) {
  int i = blockIdx.x * 256 + threadIdx.x;
  if (i < N) {
    int b = batch[i];
    int pb = (i == 0) ? -1 : batch[i - 1];
    for (int bb = pb + 1; bb <= b; bb++) bstart[bb] = i;
    if (i == N - 1)
      for (int bb = b + 1; bb <= B; bb++) bstart[bb] = N;
  }
}

// ---------- small transpose ----------
__global__ void K256 k_trans(const float* __restrict__ in, float* __restrict__ out, int R, int C) {
  int i = blockIdx.x * 256 + threadIdx.x;
  if (i < R * C) {
    int r = i / C, c = i - r * C;
    out[c * R + r] = in[i];
  }
}

// ---------- gather aggregation: wave per node, float2 lanes, 2-deep edge ILP ----------
template <int D, bool MEAN>
__global__ void K256 k_gatherv(const float* __restrict__ x, const int* __restrict__ starts,
                               const int* __restrict__ deg, const int* __restrict__ csr,
                               float* __restrict__ out, int N, int ostride) {
  constexpr int NF2 = D / 2;
  int wid = (blockIdx.x * 256 + threadIdx.x) >> 6;
  int lane = threadIdx.x & 63;
  if (wid >= N) return;
  int s = starts[wid], d = deg[wid];
  const int* cp = csr + s;
  float ax = 0.f, ay = 0.f;
  if constexpr (NF2 <= 32) {
    int half = lane >> 5, sl = lane & 31;
    bool act = sl < NF2;
    float bx = 0.f, by = 0.f;
    int j = 0;
    for (; j + 4 <= d; j += 4) {
      if (act) {
        const float2* r0 = (const float2*)(x + (size_t)cp[j + half] * D);
        const float2* r1 = (const float2*)(x + (size_t)cp[j + 2 + half] * D);
        float2 v0 = r0[sl];
        float2 v1 = r1[sl];
        ax += v0.x;
        ay += v0.y;
        bx += v1.x;
        by += v1.y;
      }
    }
    for (; j < d; j += 2) {
      int e = j + half;
      if (e < d && act) {
        const float2* row = (const float2*)(x + (size_t)cp[e] * D);
        float2 v = row[sl];
        ax += v.x;
        ay += v.y;
      }
    }
    ax += bx;
    ay += by;
    ax += __shfl_xor(ax, 32, 64);
    ay += __shfl_xor(ay, 32, 64);
    if (half == 0 && act) {
      float inv = MEAN ? 1.f / fmaxf((float)d, 1.f) : 1.f;
      float2* op = (float2*)(out + (size_t)wid * ostride);
      float2 w;
      w.x = ax * inv;
      w.y = ay * inv;
      op[sl] = w;
    }
  } else {
    bool act = lane < NF2;
    float bx = 0.f, by = 0.f;
    int j = 0;
    for (; j + 2 <= d; j += 2) {
      if (act) {
        const float2* r0 = (const float2*)(x + (size_t)cp[j] * D);
        const float2* r1 = (const float2*)(x + (size_t)cp[j + 1] * D);
        float2 v0 = r0[lane];
        float2 v1 = r1[lane];
        ax += v0.x;
        ay += v0.y;
        bx += v1.x;
        by += v1.y;
      }
    }
    if (j < d && act) {
      const float2* row = (const float2*)(x + (size_t)cp[j] * D);
      float2 v = row[lane];
      ax += v.x;
      ay += v.y;
    }
    ax += bx;
    ay += by;
    if (act) {
      float inv = MEAN ? 1.f / fmaxf((float)d, 1.f) : 1.f;
      float2* op = (float2*)(out + (size_t)wid * ostride);
      float2 w;
      w.x = ax * inv;
      w.y = ay * inv;
      op[lane] = w;
    }
  }
}

// ---------- segmented pooling ----------
template <int D, int NPB, bool ACCUM>
__global__ void K256 k_pool_seg(const float* __restrict__ x, const int* __restrict__ bstart,
                                float* __restrict__ pooled, float coef) {
  __shared__ float sp[D * NPB];
  int b = blockIdx.x, tid = threadIdx.x;
  int r0 = bstart[b], r1 = bstart[b + 1];
  if (tid < D * NPB) {
    int ioff = tid / D, f = tid - ioff * D;
    float acc = 0.f;
    for (int i = r0 + ioff; i < r1; i += NPB) acc += x[(size_t)i * D + f];
    sp[tid] = acc;
  }
  __syncthreads();
  if (tid < D) {
    float s = 0.f;
#pragma unroll
    for (int g = 0; g < NPB; g++) s += sp[g * D + tid];
    s *= coef;
    if (ACCUM)
      pooled[b * D + tid] += s;
    else
      pooled[b * D + tid] = s;
  }
}

// ---------- SAGE conv1: LDS-staged tile, lane=node, SGPR-uniform output half ----------
__global__ void __launch_bounds__(256, 2) k_sage1_lds(
    const float* __restrict__ x, const float* __restrict__ agg,
    const float* __restrict__ WlT, const float* __restrict__ bl,
    const float* __restrict__ WrT, float* __restrict__ out, int N) {
  __shared__ float sx[128 * DPK];
  __shared__ float sa[128 * DPK];
  int base = blockIdx.x * 128;
  int nn = min(N - base, 128);
  int tid = threadIdx.x;
  int cnt2 = nn * (DPK / 2);
  const float2* xg = (const float2*)(x + (size_t)base * DPK);
  const float2* ag = (const float2*)(agg + (size_t)base * DPK);
  for (int t = tid; t < cnt2; t += 256) {
    ((float2*)sx)[t] = xg[t];
    ((float2*)sa)[t] = ag[t];
  }
  __syncthreads();
  int w = tid >> 6, lane = tid & 63;
  // wave-uniform output half, hoisted to SGPR so weight loads scalarize (s_load)
  int obase = __builtin_amdgcn_readfirstlane((w & 1) * 27);
  int node = (w >> 1) * 64 + lane;
  if (node >= nn) return;
  const float* blu = bl + obase;
  const float* wlb = WlT + obase;
  const float* wrb = WrT + obase;
  float acc[27];
#pragma unroll
  for (int o = 0; o < 27; o++) acc[o] = blu[o];
  const float* rx = sx + node * DPK;
  const float* ra = sa + node * DPK;
#pragma unroll 2
  for (int k = 0; k < DPK; k++) {
    float xv = rx[k], av = ra[k];
    const float* wl = wlb + k * DPK;
    const float* wr = wrb + k * DPK;
#pragma unroll
    for (int o = 0; o < 27; o++) acc[o] += av * wl[o] + xv * wr[o];
  }
  float* op = out + (size_t)(base + node) * DPK + obase;
#pragma unroll
  for (int o = 0; o < 27; o++) op[o] = fmaxf(acc[o], 0.f);
}

// ---------- conv2 + segment-mean pool: LDS-staged tiles, SGPR-uniform output half ----------
template <int SPLIT>
__global__ void __launch_bounds__(256, 2) k_sage2_lds(
    const float* __restrict__ xt1, const float* __restrict__ agg,
    const float* __restrict__ WlT, const float* __restrict__ bl,
    const float* __restrict__ WrT, const int* __restrict__ bstart,
    float* __restrict__ pooled) {
  constexpr int OH = DP2 / 2;  // 54 outputs per wave-half
  __shared__ float sx[128 * DPK];
  __shared__ float sa[128 * DPK];
  int b = blockIdx.x / SPLIT;
  int sidx = blockIdx.x - b * SPLIT;
  int tid = threadIdx.x;
  int w = tid >> 6, lane = tid & 63;
  int obase = __builtin_amdgcn_readfirstlane((w & 1) * OH);
  int lnode = (w >> 1) * 64 + lane;
  const float* blu = bl + obase;
  const float* wlb = WlT + obase;
  const float* wrb = WrT + obase;
  int r0 = bstart[b], r1 = bstart[b + 1];
  int len = r1 - r0;
  int per = (len + SPLIT - 1) / SPLIT;
  int s0 = r0 + sidx * per;
  int s1 = min(r1, s0 + per);
  float pool[OH];
#pragma unroll
  for (int o = 0; o < OH; o++) pool[o] = 0.f;
  for (int tb = s0; tb < s1; tb += 128) {
    int nn = min(s1 - tb, 128);
    int cnt2 = nn * (DPK / 2);
    const float2* xg = (const float2*)(xt1 + (size_t)tb * DPK);
    const float2* ag = (const float2*)(agg + (size_t)tb * DPK);
    __syncthreads();
    for (int t = tid; t < cnt2; t += 256) {
      ((float2*)sx)[t] = xg[t];
      ((float2*)sa)[t] = ag[t];
    }
    __syncthreads();
    if (lnode < nn) {
      float acc[OH];
#pragma unroll
      for (int o = 0; o < OH; o++) acc[o] = blu[o];
      const float* rx = sx + lnode * DPK;
      const float* ra = sa + lnode * DPK;
#pragma unroll 2
      for (int k = 0; k < DPK; k++) {
        float xv = rx[k], av = ra[k];
        const float* wl = wlb + k * DP2;
        const float* wr = wrb + k * DP2;
#pragma unroll
        for (int o = 0; o < OH; o++) acc[o] += av * wl[o] + xv * wr[o];
      }
#pragma unroll
      for (int o = 0; o < OH; o++) pool[o] += fmaxf(acc[o], 0.f);
    }
  }
#pragma unroll
  for (int o = 0; o < OH; o++) {
#pragma unroll
    for (int off = 1; off < 64; off <<= 1) pool[o] += __shfl_xor(pool[o], off, 64);
  }
  if (lane == 0) {
    float* pb = pooled + b * DP2 + obase;
#pragma unroll
    for (int o = 0; o < OH; o++)
      if (pool[o] != 0.f) atomicAdd(&pb[o], pool[o]);
  }
}

// ---------- branch head MLP ----------
template <int DIN, int DOUT>
__global__ void K256 k_head(const float* __restrict__ pooled, const int* __restrict__ bstart,
                            const float* __restrict__ W1, const float* __restrict__ b1,
                            const float* __restrict__ W2, const float* __restrict__ b2,
                            float* __restrict__ outv) {
  __shared__ float sx[DIN];
  __shared__ float sh[256];
  int b = blockIdx.x, tid = threadIdx.x;
  float inv = 1.f / fmaxf((float)(bstart[b + 1] - bstart[b]), 1.f);
  for (int f = tid; f < DIN; f += 256) sx[f] = pooled[b * DIN + f] * inv;
  __syncthreads();
  float acc = b1[tid];
#pragma unroll 2
  for (int k = 0; k < DIN; k++) acc += sx[k] * W1[tid * DIN + k];
  sh[tid] = fmaxf(acc, 0.f);
  __syncthreads();
  if (tid < DOUT) {
    float a = b2[tid];
#pragma unroll 4
    for (int k = 0; k < 256; k++) a += sh[k] * W2[tid * 256 + k];
    outv[b * DOUT + tid] = a;
  }
}

// ---------- final MLP ----------
__global__ void K256 k_final(const float* __restrict__ molv, const float* __restrict__ prov,
                             const float* __restrict__ W1, const float* __restrict__ b1,
                             const float* __restrict__ W2, const float* __restrict__ b2,
                             const float* __restrict__ W3, const float* __restrict__ b3,
                             float* __restrict__ out) {
  __shared__ float sx[256];
  __shared__ float sh1[1024];
  __shared__ float sh2[512];
  __shared__ float red[4];
  int b = blockIdx.x, tid = threadIdx.x;
  sx[tid] = (tid < 112) ? molv[b * 112 + tid] : prov[b * 144 + (tid - 112)];
  __syncthreads();
  for (int o = tid; o < 1024; o += 256) {
    float a = b1[o];
#pragma unroll 4
    for (int k = 0; k < 256; k++) a += sx[k] * W1[o * 256 + k];
    sh1[o] = fmaxf(a, 0.f);
  }
  __syncthreads();
  for (int o = tid; o < 512; o += 256) {
    float a = b2[o];
#pragma unroll 4
    for (int k = 0; k < 1024; k++) a += sh1[k] * W2[o * 1024 + k];
    sh2[o] = fmaxf(a, 0.f);
  }
  __syncthreads();
  float a = 0.f;
  for (int k = tid; k < 512; k += 256) a += sh2[k] * W3[k];
  for (int off = 32; off > 0; off >>= 1) a += __shfl_down(a, off, 64);
  if ((tid & 63) == 0) red[tid >> 6] = a;
  __syncthreads();
  if (tid == 0) out[b] = red[0] + red[1] + red[2] + red[3] + b3[0];
}

__global__ void k_report(float* out, float v, int n) {
  int i = blockIdx.x * 256 + threadIdx.x;
  if (i < n) out[i] = v;
}

extern "C" void kernel_launch(void* const* d_in, const int* in_sizes, int n_in,
                              void* d_out, int out_size, void* d_ws, size_t ws_size,
                              hipStream_t stream) {
  (void)in_sizes; (void)n_in;
  const float* mol_x = (const float*)d_in[0];
  const int* m_ei = (const int*)d_in[1];
  const int* m_batch = (const int*)d_in[2];
  const float* pro_x = (const float*)d_in[3];
  const int* p_ei = (const int*)d_in[4];
  const int* p_batch = (const int*)d_in[5];
  const float* mol_W1 = (const float*)d_in[6];
  const float* mol_b1 = (const float*)d_in[7];
  const float* mol_W2 = (const float*)d_in[8];
  const float* mol_b2 = (const float*)d_in[9];
  const float* c1_Wl = (const float*)d_in[10];
  const float* c1_bl = (const float*)d_in[11];
  const float* c1_Wr = (const float*)d_in[12];
  const float* c2_Wl = (const float*)d_in[13];
  const float* c2_bl = (const float*)d_in[14];
  const float* c2_Wr = (const float*)d_in[15];
  const float* pro_W1 = (const float*)d_in[16];
  const float* pro_b1 = (const float*)d_in[17];
  const float* pro_W2 = (const float*)d_in[18];
  const float* pro_b2 = (const float*)d_in[19];
  const float* fc1_W = (const float*)d_in[20];
  const float* fc1_b = (const float*)d_in[21];
  const float* fc2_W = (const float*)d_in[22];
  const float* fc2_b = (const float*)d_in[23];
  const float* out_W = (const float*)d_in[24];
  const float* out_b = (const float*)d_in[25];
  float* out = (float*)d_out;
  char* ws = (char*)d_ws;

  const int* m_row = m_ei;       // dst
  const int* m_col = m_ei + EM;  // src
  const int* p_e0 = p_ei;        // src
  const int* p_e1 = p_ei + EP;   // dst

  auto al = [](size_t x) { return (x + 255) & ~(size_t)255; };

  size_t o = 0;
  size_t o_pdeg = o;   o += al((size_t)NP * 4);
  size_t o_pincl = o;  o += al((size_t)NP * 4);
  size_t o_pstart = o; o += al((size_t)NP * 4);
  size_t o_pbsum = o;  o += al(1024);
  size_t o_pcsr = o;   o += al((size_t)EP * 4);
  size_t o_agg = o;    o += al((size_t)NP * DPK * 4);  // also pro binned
  size_t o_xt1 = o;    o += al((size_t)NP * DPK * 4);
  size_t pro_end = o;

  o = 0;
  size_t o_mdeg = o;   o += al((size_t)NM * 4);
  size_t o_mincl = o;  o += al((size_t)NM * 4);
  size_t o_mstart = o; o += al((size_t)NM * 4);
  size_t o_mbsum = o;  o += al(1024);
  size_t o_mcsr = o;   o += al((size_t)EM * 4);
  size_t o_hA = o;     o += al((size_t)NM * DM * 4);  // also mol binned
  size_t o_hB = o;     o += al((size_t)NM * DM * 4);
  size_t mol_end = o;

  size_t tail = al(pro_end > mol_end ? pro_end : mol_end);
  size_t o_poolM = tail; tail += al((size_t)B * DM * 4);
  size_t o_poolP = tail; tail += al((size_t)B * DP2 * 4);
  size_t o_molv = tail;  tail += al((size_t)B * 112 * 4);
  size_t o_prov = tail;  tail += al((size_t)B * 144 * 4);
  size_t o_mbs = tail;   tail += al((size_t)(B + 1) * 4);
  size_t o_pbs = tail;   tail += al((size_t)(B + 1) * 4);
  size_t o_w1l = tail;   tail += al((size_t)DPK * DPK * 4);
  size_t o_w1r = tail;   tail += al((size_t)DPK * DPK * 4);
  size_t o_w2l = tail;   tail += al((size_t)DPK * DP2 * 4);
  size_t o_w2r = tail;   tail += al((size_t)DPK * DP2 * 4);
  size_t o_mbc = tail;   tail += al(512 * 4);
  size_t o_pbc = tail;   tail += al(512 * 4);

  if (ws_size < tail) {
    k_report<<<1, 256, 0, stream>>>(out, (float)(ws_size >> 20), out_size);
    return;
  }

  int* mdeg = (int*)(ws + o_mdeg);
  int* mincl = (int*)(ws + o_mincl);
  int* mstart = (int*)(ws + o_mstart);
  int* mbsum = (int*)(ws + o_mbsum);
  int* mcsr = (int*)(ws + o_mcsr);
  float* hA = (float*)(ws + o_hA);
  float* hB = (float*)(ws + o_hB);
  int* pdeg = (int*)(ws + o_pdeg);
  int* pincl = (int*)(ws + o_pincl);
  int* pstart = (int*)(ws + o_pstart);
  int* pbsum = (int*)(ws + o_pbsum);
  int* pcsr = (int*)(ws + o_pcsr);
  float* agg = (float*)(ws + o_agg);
  float* xt1 = (float*)(ws + o_xt1);
  float* poolM = (float*)(ws + o_poolM);
  float* poolP = (float*)(ws + o_poolP);
  float* molv = (float*)(ws + o_molv);
  float* prov = (float*)(ws + o_prov);
  int* mbs = (int*)(ws + o_mbs);
  int* pbs = (int*)(ws + o_pbs);
  float* w1l = (float*)(ws + o_w1l);
  float* w1r = (float*)(ws + o_w1r);
  float* w2l = (float*)(ws + o_w2l);
  float* w2r = (float*)(ws + o_w2r);
  int* mbc = (int*)(ws + o_mbc);
  int* pbc = (int*)(ws + o_pbc);
  int2* mbinned = (int2*)hA;
  int2* pbinned = (int2*)agg;

  // weight transposes (tiny)
  k_trans<<<(DPK * DPK + 255) / 256, 256, 0, stream>>>(c1_Wl, w1l, DPK, DPK);
  k_trans<<<(DPK * DPK + 255) / 256, 256, 0, stream>>>(c1_Wr, w1r, DPK, DPK);
  k_trans<<<(DP2 * DPK + 255) / 256, 256, 0, stream>>>(c2_Wl, w2l, DP2, DPK);
  k_trans<<<(DP2 * DPK + 255) / 256, 256, 0, stream>>>(c2_Wr, w2r, DP2, DPK);

  // ===== MOL branch =====
  constexpr int SHM = 8;
  constexpr int NBM = (NM + (1 << SHM) - 1) >> SHM;
  hipMemsetAsync(mdeg, 0, (size_t)NM * 4, stream);
  k_count4<<<(EM / 4 + 255) / 256, 256, 0, stream>>>((const int4*)m_row, mdeg, EM / 4);
  int nb_m = (NM + 1023) / 1024;
  k_scan1<<<nb_m, 1024, 0, stream>>>(mdeg, mincl, mbsum, NM);
  k_scan2<<<1, 256, 0, stream>>>(mbsum, nb_m);
  k_scan3<<<(NM + 255) / 256, 256, 0, stream>>>(mincl, mdeg, mbsum, mstart, NM);
  k_bcur<SHM><<<(NBM + 255) / 256, 256, 0, stream>>>(mstart, mbc, NM);
  k_bin<SHM><<<(EM + 4095) / 4096, 256, 0, stream>>>(m_col, m_row, mbc, mbinned, EM);
  k_fill2<SHM><<<NBM, 256, 0, stream>>>(mbinned, mstart, mcsr, NM, EM);
  k_bstart<<<(NM + 255) / 256, 256, 0, stream>>>(m_batch, mbs, NM);

  int gb_m = (NM * 64 + 255) / 256;
  k_pool_seg<DM, 3, false><<<B, 256, 0, stream>>>(mol_x, mbs, poolM, 0.05f);
  k_gatherv<DM, false><<<gb_m, 256, 0, stream>>>(mol_x, mstart, mdeg, mcsr, hA, NM, DM);
  k_pool_seg<DM, 3, true><<<B, 256, 0, stream>>>(hA, mbs, poolM, 0.2375f);
  k_gatherv<DM, false><<<gb_m, 256, 0, stream>>>(hA, mstart, mdeg, mcsr, hB, NM, DM);
  k_pool_seg<DM, 3, true><<<B, 256, 0, stream>>>(hB, mbs, poolM, 0.2375f);
  k_gatherv<DM, false><<<gb_m, 256, 0, stream>>>(hB, mstart, mdeg, mcsr, hA, NM, DM);
  k_pool_seg<DM, 3, true><<<B, 256, 0, stream>>>(hA, mbs, poolM, 0.2375f);
  k_gatherv<DM, false><<<gb_m, 256, 0, stream>>>(hA, mstart, mdeg, mcsr, hB, NM, DM);
  k_pool_seg<DM, 3, true><<<B, 256, 0, stream>>>(hB, mbs, poolM, 0.2375f);
  k_head<DM, 112><<<B, 256, 0, stream>>>(poolM, mbs, mol_W1, mol_b1, mol_W2, mol_b2, molv);

  // ===== PRO branch =====
  constexpr int SHP = 9;
  constexpr int NBP = (NP + (1 << SHP) - 1) >> SHP;
  hipMemsetAsync(pdeg, 0, (size_t)NP * 4, stream);
  hipMemsetAsync(poolP, 0, (size_t)B * DP2 * 4, stream);
  k_count4<<<(EP / 4 + 255) / 256, 256, 0, stream>>>((const int4*)p_e1, pdeg, EP / 4);
  int nb_p = (NP + 1023) / 1024;
  k_scan1<<<nb_p, 1024, 0, stream>>>(pdeg, pincl, pbsum, NP);
  k_scan2<<<1, 256, 0, stream>>>(pbsum, nb_p);
  k_scan3<<<(NP + 255) / 256, 256, 0, stream>>>(pincl, pdeg, pbsum, pstart, NP);
  k_bcur<SHP><<<(NBP + 255) / 256, 256, 0, stream>>>(pstart, pbc, NP);
  k_bin<SHP><<<(EP + 4095) / 4096, 256, 0, stream>>>(p_e0, p_e1, pbc, pbinned, EP);
  k_fill2<SHP><<<NBP, 256, 0, stream>>>(pbinned, pstart, pcsr, NP, EP);
  k_bstart<<<(NP + 255) / 256, 256, 0, stream>>>(p_batch, pbs, NP);

  int gb_p = (NP * 64 + 255) / 256;
  k_gatherv<DPK, true><<<gb_p, 256, 0, stream>>>(pro_x, pstart, pdeg, pcsr, agg, NP, DPK);
  k_sage1_lds<<<(NP + 127) / 128, 256, 0, stream>>>(pro_x, agg, w1l, c1_bl, w1r, xt1, NP);
  k_gatherv<DPK, true><<<gb_p, 256, 0, stream>>>(xt1, pstart, pdeg, pcsr, agg, NP, DPK);
  k_sage2_lds<4><<<B * 4, 256, 0, stream>>>(xt1, agg, w2l, c2_bl, w2r, pbs, poolP);
  k_head<DP2, 144><<<B, 256, 0, stream>>>(poolP, pbs, pro_W1, pro_b1, pro_W2, pro_b2, prov);

  k_final<<<B, 256, 0, stream>>>(molv, prov, fc1_W, fc1_b, fc2_W, fc2_b, out_W, out_b, out);
}

// Round 7
// 1522.637 us; speedup vs baseline: 1.2619x; 1.0079x over previous
//
#include <hip/hip_runtime.h>

#define K256 __launch_bounds__(256)

constexpr int B = 128;
constexpr int NM = 100000, EM = 400000;
constexpr int NP = 200000, EP = 3200000;
constexpr int DM = 78, DPK = 54, DP2 = 108;

// ---------- CSR build ----------
__global__ void K256 k_count4(const int4* __restrict__ dst, int* __restrict__ deg, int E4) {
  int e = blockIdx.x * 256 + threadIdx.x;
  if (e < E4) {
    int4 v = dst[e];
    atomicAdd(&deg[v.x], 1);
    atomicAdd(&deg[v.y], 1);
    atomicAdd(&deg[v.z], 1);
    atomicAdd(&deg[v.w], 1);
  }
}

__global__ void k_scan1(const int* __restrict__ deg, int* __restrict__ incl,
                        int* __restrict__ bsum, int N) {
  __shared__ int s[1024];
  int i = blockIdx.x * 1024 + threadIdx.x;
  int v = (i < N) ? deg[i] : 0;
  s[threadIdx.x] = v;
  __syncthreads();
  for (int off = 1; off < 1024; off <<= 1) {
    int t = (threadIdx.x >= off) ? s[threadIdx.x - off] : 0;
    __syncthreads();
    s[threadIdx.x] += t;
    __syncthreads();
  }
  if (i < N) incl[i] = s[threadIdx.x];
  if (threadIdx.x == 1023) bsum[blockIdx.x] = s[1023];
}

__global__ void k_scan2(int* __restrict__ bsum, int nb) {
  __shared__ int s[256];
  int v = (threadIdx.x < (unsigned)nb) ? bsum[threadIdx.x] : 0;
  s[threadIdx.x] = v;
  __syncthreads();
  for (int off = 1; off < 256; off <<= 1) {
    int t = (threadIdx.x >= off) ? s[threadIdx.x - off] : 0;
    __syncthreads();
    s[threadIdx.x] += t;
    __syncthreads();
  }
  if (threadIdx.x < (unsigned)nb) bsum[threadIdx.x] = s[threadIdx.x] - v;  // exclusive
}

__global__ void K256 k_scan3(const int* __restrict__ incl, const int* __restrict__ deg,
                             const int* __restrict__ bsum, int* __restrict__ starts, int N) {
  int i = blockIdx.x * 256 + threadIdx.x;
  if (i < N) starts[i] = incl[i] - deg[i] + bsum[i >> 10];
}

template <int SH>
__global__ void K256 k_bcur(const int* __restrict__ starts, int* __restrict__ bcur, int N) {
  int b = blockIdx.x * 256 + threadIdx.x;
  int NB = (N + (1 << SH) - 1) >> SH;
  if (b < NB) bcur[b] = starts[b << SH];
}

// Pass A: bucket-grouped edge binning (counting-sort per 4096-edge chunk).
template <int SH>
__global__ void K256 k_bin(const int* __restrict__ src, const int* __restrict__ dst,
                           int* __restrict__ bcur, int2* __restrict__ binned, int E) {
  __shared__ int lh[512];
  __shared__ int gbase[512];
  int c0 = blockIdx.x * 4096;
  int tid = threadIdx.x;
  for (int t = tid; t < 512; t += 256) lh[t] = 0;
  __syncthreads();
  int r[16], dcache[16];
#pragma unroll
  for (int k = 0; k < 16; k++) {
    int e = c0 + k * 256 + tid;
    if (e < E) {
      int d = dst[e];
      dcache[k] = d;
      r[k] = atomicAdd(&lh[d >> SH], 1);
    }
  }
  __syncthreads();
  for (int b = tid; b < 512; b += 256) {
    int c = lh[b];
    gbase[b] = c ? atomicAdd(&bcur[b], c) : 0;
  }
  __syncthreads();
#pragma unroll
  for (int k = 0; k < 16; k++) {
    int e = c0 + k * 256 + tid;
    if (e < E) {
      int d = dcache[k];
      binned[gbase[d >> SH] + r[k]] = make_int2(src[e], d);
    }
  }
}

// Pass B: per-bucket CSR fill; node cursors in LDS.
template <int SH>
__global__ void K256 k_fill2(const int2* __restrict__ binned, const int* __restrict__ starts,
                             int* __restrict__ csr, int N, int E) {
  __shared__ int lcur[1 << SH];
  int b = blockIdx.x;
  int base = b << SH;
  int nn = min(N - base, 1 << SH);
  int tid = threadIdx.x;
  for (int t = tid; t < nn; t += 256) lcur[t] = starts[base + t];
  __syncthreads();
  int r0 = starts[base];
  int r1 = (base + (1 << SH) >= N) ? E : starts[base + (1 << SH)];
  for (int e = r0 + tid; e < r1; e += 256) {
    int2 sd = binned[e];
    int p = atomicAdd(&lcur[sd.y - base], 1);
    csr[p] = sd.x;
  }
}

// ---------- batch segment starts (batch is sorted) ----------
__global__ void K256 k_bstart(const int* __restrict__ batch, int* __restrict__ bstart, int N) {
  int i = blockIdx.x * 256 + threadIdx.x;
  if (i < N) {
    int b = batch[i];
    int pb = (i == 0) ? -1 : batch[i - 1];
    for (int bb = pb + 1; bb <= b; bb++) bstart[bb] = i;
    if (i == N - 1)
      for (int bb = b + 1; bb <= B; bb++) bstart[bb] = N;
  }
}

// ---------- small transpose ----------
__global__ void K256 k_trans(const float* __restrict__ in, float* __restrict__ out, int R, int C) {
  int i = blockIdx.x * 256 + threadIdx.x;
  if (i < R * C) {
    int r = i / C, c = i - r * C;
    out[c * R + r] = in[i];
  }
}

// ---------- gather aggregation: wave per node, float2 lanes, 2-deep edge ILP ----------
template <int D, bool MEAN>
__global__ void K256 k_gatherv(const float* __restrict__ x, const int* __restrict__ starts,
                               const int* __restrict__ deg, const int* __restrict__ csr,
                               float* __restrict__ out, int N, int ostride) {
  constexpr int NF2 = D / 2;
  int wid = (blockIdx.x * 256 + threadIdx.x) >> 6;
  int lane = threadIdx.x & 63;
  if (wid >= N) return;
  int s = starts[wid], d = deg[wid];
  const int* cp = csr + s;
  float ax = 0.f, ay = 0.f;
  if constexpr (NF2 <= 32) {
    int half = lane >> 5, sl = lane & 31;
    bool act = sl < NF2;
    float bx = 0.f, by = 0.f;
    int j = 0;
    for (; j + 4 <= d; j += 4) {
      if (act) {
        const float2* r0 = (const float2*)(x + (size_t)cp[j + half] * D);
        const float2* r1 = (const float2*)(x + (size_t)cp[j + 2 + half] * D);
        float2 v0 = r0[sl];
        float2 v1 = r1[sl];
        ax += v0.x;
        ay += v0.y;
        bx += v1.x;
        by += v1.y;
      }
    }
    for (; j < d; j += 2) {
      int e = j + half;
      if (e < d && act) {
        const float2* row = (const float2*)(x + (size_t)cp[e] * D);
        float2 v = row[sl];
        ax += v.x;
        ay += v.y;
      }
    }
    ax += bx;
    ay += by;
    ax += __shfl_xor(ax, 32, 64);
    ay += __shfl_xor(ay, 32, 64);
    if (half == 0 && act) {
      float inv = MEAN ? 1.f / fmaxf((float)d, 1.f) : 1.f;
      float2* op = (float2*)(out + (size_t)wid * ostride);
      float2 w;
      w.x = ax * inv;
      w.y = ay * inv;
      op[sl] = w;
    }
  } else {
    bool act = lane < NF2;
    float bx = 0.f, by = 0.f;
    int j = 0;
    for (; j + 2 <= d; j += 2) {
      if (act) {
        const float2* r0 = (const float2*)(x + (size_t)cp[j] * D);
        const float2* r1 = (const float2*)(x + (size_t)cp[j + 1] * D);
        float2 v0 = r0[lane];
        float2 v1 = r1[lane];
        ax += v0.x;
        ay += v0.y;
        bx += v1.x;
        by += v1.y;
      }
    }
    if (j < d && act) {
      const float2* row = (const float2*)(x + (size_t)cp[j] * D);
      float2 v = row[lane];
      ax += v.x;
      ay += v.y;
    }
    ax += bx;
    ay += by;
    if (act) {
      float inv = MEAN ? 1.f / fmaxf((float)d, 1.f) : 1.f;
      float2* op = (float2*)(out + (size_t)wid * ostride);
      float2 w;
      w.x = ax * inv;
      w.y = ay * inv;
      op[lane] = w;
    }
  }
}

// ---------- segmented pooling ----------
template <int D, int NPB, bool ACCUM>
__global__ void K256 k_pool_seg(const float* __restrict__ x, const int* __restrict__ bstart,
                                float* __restrict__ pooled, float coef) {
  __shared__ float sp[D * NPB];
  int b = blockIdx.x, tid = threadIdx.x;
  int r0 = bstart[b], r1 = bstart[b + 1];
  if (tid < D * NPB) {
    int ioff = tid / D, f = tid - ioff * D;
    float acc = 0.f;
    for (int i = r0 + ioff; i < r1; i += NPB) acc += x[(size_t)i * D + f];
    sp[tid] = acc;
  }
  __syncthreads();
  if (tid < D) {
    float s = 0.f;
#pragma unroll
    for (int g = 0; g < NPB; g++) s += sp[g * D + tid];
    s *= coef;
    if (ACCUM)
      pooled[b * D + tid] += s;
    else
      pooled[b * D + tid] = s;
  }
}

// ---------- SAGE conv1: LDS-staged tile, lane=node, SGPR-uniform output half ----------
__global__ void __launch_bounds__(256, 2) k_sage1_lds(
    const float* __restrict__ x, const float* __restrict__ agg,
    const float* __restrict__ WlT, const float* __restrict__ bl,
    const float* __restrict__ WrT, float* __restrict__ out, int N) {
  __shared__ float sx[128 * DPK];
  __shared__ float sa[128 * DPK];
  int base = blockIdx.x * 128;
  int nn = min(N - base, 128);
  int tid = threadIdx.x;
  int cnt2 = nn * (DPK / 2);
  const float2* xg = (const float2*)(x + (size_t)base * DPK);
  const float2* ag = (const float2*)(agg + (size_t)base * DPK);
  for (int t = tid; t < cnt2; t += 256) {
    ((float2*)sx)[t] = xg[t];
    ((float2*)sa)[t] = ag[t];
  }
  __syncthreads();
  int w = tid >> 6, lane = tid & 63;
  // wave-uniform output half, hoisted to SGPR so weight loads scalarize (s_load)
  int obase = __builtin_amdgcn_readfirstlane((w & 1) * 27);
  int node = (w >> 1) * 64 + lane;
  if (node >= nn) return;
  const float* blu = bl + obase;
  const float* wlb = WlT + obase;
  const float* wrb = WrT + obase;
  float acc[27];
#pragma unroll
  for (int o = 0; o < 27; o++) acc[o] = blu[o];
  const float* rx = sx + node * DPK;
  const float* ra = sa + node * DPK;
#pragma unroll 2
  for (int k = 0; k < DPK; k++) {
    float xv = rx[k], av = ra[k];
    const float* wl = wlb + k * DPK;
    const float* wr = wrb + k * DPK;
#pragma unroll
    for (int o = 0; o < 27; o++) acc[o] += av * wl[o] + xv * wr[o];
  }
  float* op = out + (size_t)(base + node) * DPK + obase;
#pragma unroll
  for (int o = 0; o < 27; o++) op[o] = fmaxf(acc[o], 0.f);
}

// ---------- conv2 + segment-mean pool: LDS-staged tiles, SGPR-uniform output half ----------
template <int SPLIT>
__global__ void __launch_bounds__(256, 2) k_sage2_lds(
    const float* __restrict__ xt1, const float* __restrict__ agg,
    const float* __restrict__ WlT, const float* __restrict__ bl,
    const float* __restrict__ WrT, const int* __restrict__ bstart,
    float* __restrict__ pooled) {
  constexpr int OH = DP2 / 2;  // 54 outputs per wave-half
  __shared__ float sx[128 * DPK];
  __shared__ float sa[128 * DPK];
  int b = blockIdx.x / SPLIT;
  int sidx = blockIdx.x - b * SPLIT;
  int tid = threadIdx.x;
  int w = tid >> 6, lane = tid & 63;
  int obase = __builtin_amdgcn_readfirstlane((w & 1) * OH);
  int lnode = (w >> 1) * 64 + lane;
  const float* blu = bl + obase;
  const float* wlb = WlT + obase;
  const float* wrb = WrT + obase;
  int r0 = bstart[b], r1 = bstart[b + 1];
  int len = r1 - r0;
  int per = (len + SPLIT - 1) / SPLIT;
  int s0 = r0 + sidx * per;
  int s1 = min(r1, s0 + per);
  float pool[OH];
#pragma unroll
  for (int o = 0; o < OH; o++) pool[o] = 0.f;
  for (int tb = s0; tb < s1; tb += 128) {
    int nn = min(s1 - tb, 128);
    int cnt2 = nn * (DPK / 2);
    const float2* xg = (const float2*)(xt1 + (size_t)tb * DPK);
    const float2* ag = (const float2*)(agg + (size_t)tb * DPK);
    __syncthreads();
    for (int t = tid; t < cnt2; t += 256) {
      ((float2*)sx)[t] = xg[t];
      ((float2*)sa)[t] = ag[t];
    }
    __syncthreads();
    if (lnode < nn) {
      float acc[OH];
#pragma unroll
      for (int o = 0; o < OH; o++) acc[o] = blu[o];
      const float* rx = sx + lnode * DPK;
      const float* ra = sa + lnode * DPK;
#pragma unroll 2
      for (int k = 0; k < DPK; k++) {
        float xv = rx[k], av = ra[k];
        const float* wl = wlb + k * DP2;
        const float* wr = wrb + k * DP2;
#pragma unroll
        for (int o = 0; o < OH; o++) acc[o] += av * wl[o] + xv * wr[o];
      }
#pragma unroll
      for (int o = 0; o < OH; o++) pool[o] += fmaxf(acc[o], 0.f);
    }
  }
#pragma unroll
  for (int o = 0; o < OH; o++) {
#pragma unroll
    for (int off = 1; off < 64; off <<= 1) pool[o] += __shfl_xor(pool[o], off, 64);
  }
  if (lane == 0) {
    float* pb = pooled + b * DP2 + obase;
#pragma unroll
    for (int o = 0; o < OH; o++)
      if (pool[o] != 0.f) atomicAdd(&pb[o], pool[o]);
  }
}

// ---------- branch head MLP ----------
template <int DIN, int DOUT>
__global__ void K256 k_head(const float* __restrict__ pooled, const int* __restrict__ bstart,
                            const float* __restrict__ W1, const float* __restrict__ b1,
                            const float* __restrict__ W2, const float* __restrict__ b2,
                            float* __restrict__ outv) {
  __shared__ float sx[DIN];
  __shared__ float sh[256];
  int b = blockIdx.x, tid = threadIdx.x;
  float inv = 1.f / fmaxf((float)(bstart[b + 1] - bstart[b]), 1.f);
  for (int f = tid; f < DIN; f += 256) sx[f] = pooled[b * DIN + f] * inv;
  __syncthreads();
  float acc = b1[tid];
#pragma unroll 2
  for (int k = 0; k < DIN; k++) acc += sx[k] * W1[tid * DIN + k];
  sh[tid] = fmaxf(acc, 0.f);
  __syncthreads();
  if (tid < DOUT) {
    float a = b2[tid];
#pragma unroll 4
    for (int k = 0; k < 256; k++) a += sh[k] * W2[tid * 256 + k];
    outv[b * DOUT + tid] = a;
  }
}

// ---------- final MLP ----------
__global__ void K256 k_final(const float* __restrict__ molv, const float* __restrict__ prov,
                             const float* __restrict__ W1, const float* __restrict__ b1,
                             const float* __restrict__ W2, const float* __restrict__ b2,
                             const float* __restrict__ W3, const float* __restrict__ b3,
                             float* __restrict__ out) {
  __shared__ float sx[256];
  __shared__ float sh1[1024];
  __shared__ float sh2[512];
  __shared__ float red[4];
  int b = blockIdx.x, tid = threadIdx.x;
  sx[tid] = (tid < 112) ? molv[b * 112 + tid] : prov[b * 144 + (tid - 112)];
  __syncthreads();
  for (int o = tid; o < 1024; o += 256) {
    float a = b1[o];
#pragma unroll 4
    for (int k = 0; k < 256; k++) a += sx[k] * W1[o * 256 + k];
    sh1[o] = fmaxf(a, 0.f);
  }
  __syncthreads();
  for (int o = tid; o < 512; o += 256) {
    float a = b2[o];
#pragma unroll 4
    for (int k = 0; k < 1024; k++) a += sh1[k] * W2[o * 1024 + k];
    sh2[o] = fmaxf(a, 0.f);
  }
  __syncthreads();
  float a = 0.f;
  for (int k = tid; k < 512; k += 256) a += sh2[k] * W3[k];
  for (int off = 32; off > 0; off >>= 1) a += __shfl_down(a, off, 64);
  if ((tid & 63) == 0) red[tid >> 6] = a;
  __syncthreads();
  if (tid == 0) out[b] = red[0] + red[1] + red[2] + red[3] + b3[0];
}

__global__ void k_report(float* out, float v, int n) {
  int i = blockIdx.x * 256 + threadIdx.x;
  if (i < n) out[i] = v;
}

extern "C" void kernel_launch(void* const* d_in, const int* in_sizes, int n_in,
                              void* d_out, int out_size, void* d_ws, size_t ws_size,
                              hipStream_t stream) {
  (void)in_sizes; (void)n_in;
  const float* mol_x = (const float*)d_in[0];
  const int* m_ei = (const int*)d_in[1];
  const int* m_batch = (const int*)d_in[2];
  const float* pro_x = (const float*)d_in[3];
  const int* p_ei = (const int*)d_in[4];
  const int* p_batch = (const int*)d_in[5];
  const float* mol_W1 = (const float*)d_in[6];
  const float* mol_b1 = (const float*)d_in[7];
  const float* mol_W2 = (const float*)d_in[8];
  const float* mol_b2 = (const float*)d_in[9];
  const float* c1_Wl = (const float*)d_in[10];
  const float* c1_bl = (const float*)d_in[11];
  const float* c1_Wr = (const float*)d_in[12];
  const float* c2_Wl = (const float*)d_in[13];
  const float* c2_bl = (const float*)d_in[14];
  const float* c2_Wr = (const float*)d_in[15];
  const float* pro_W1 = (const float*)d_in[16];
  const float* pro_b1 = (const float*)d_in[17];
  const float* pro_W2 = (const float*)d_in[18];
  const float* pro_b2 = (const float*)d_in[19];
  const float* fc1_W = (const float*)d_in[20];
  const float* fc1_b = (const float*)d_in[21];
  const float* fc2_W = (const float*)d_in[22];
  const float* fc2_b = (const float*)d_in[23];
  const float* out_W = (const float*)d_in[24];
  const float* out_b = (const float*)d_in[25];
  float* out = (float*)d_out;
  char* ws = (char*)d_ws;

  const int* m_row = m_ei;       // dst
  const int* m_col = m_ei + EM;  // src
  const int* p_e0 = p_ei;        // src
  const int* p_e1 = p_ei + EP;   // dst

  auto al = [](size_t x) { return (x + 255) & ~(size_t)255; };

  size_t o = 0;
  size_t o_pdeg = o;   o += al((size_t)NP * 4);
  size_t o_pincl = o;  o += al((size_t)NP * 4);
  size_t o_pstart = o; o += al((size_t)NP * 4);
  size_t o_pbsum = o;  o += al(1024);
  size_t o_pcsr = o;   o += al((size_t)EP * 4);
  size_t o_agg = o;    o += al((size_t)NP * DPK * 4);  // also pro binned
  size_t o_xt1 = o;    o += al((size_t)NP * DPK * 4);
  size_t pro_end = o;

  o = 0;
  size_t o_mdeg = o;   o += al((size_t)NM * 4);
  size_t o_mincl = o;  o += al((size_t)NM * 4);
  size_t o_mstart = o; o += al((size_t)NM * 4);
  size_t o_mbsum = o;  o += al(1024);
  size_t o_mcsr = o;   o += al((size_t)EM * 4);
  size_t o_hA = o;     o += al((size_t)NM * DM * 4);  // also mol binned
  size_t o_hB = o;     o += al((size_t)NM * DM * 4);
  size_t mol_end = o;

  size_t tail = al(pro_end > mol_end ? pro_end : mol_end);
  size_t o_poolM = tail; tail += al((size_t)B * DM * 4);
  size_t o_poolP = tail; tail += al((size_t)B * DP2 * 4);
  size_t o_molv = tail;  tail += al((size_t)B * 112 * 4);
  size_t o_prov = tail;  tail += al((size_t)B * 144 * 4);
  size_t o_mbs = tail;   tail += al((size_t)(B + 1) * 4);
  size_t o_pbs = tail;   tail += al((size_t)(B + 1) * 4);
  size_t o_w1l = tail;   tail += al((size_t)DPK * DPK * 4);
  size_t o_w1r = tail;   tail += al((size_t)DPK * DPK * 4);
  size_t o_w2l = tail;   tail += al((size_t)DPK * DP2 * 4);
  size_t o_w2r = tail;   tail += al((size_t)DPK * DP2 * 4);
  size_t o_mbc = tail;   tail += al(512 * 4);
  size_t o_pbc = tail;   tail += al(512 * 4);

  if (ws_size < tail) {
    k_report<<<1, 256, 0, stream>>>(out, (float)(ws_size >> 20), out_size);
    return;
  }

  int* mdeg = (int*)(ws + o_mdeg);
  int* mincl = (int*)(ws + o_mincl);
  int* mstart = (int*)(ws + o_mstart);
  int* mbsum = (int*)(ws + o_mbsum);
  int* mcsr = (int*)(ws + o_mcsr);
  float* hA = (float*)(ws + o_hA);
  float* hB = (float*)(ws + o_hB);
  int* pdeg = (int*)(ws + o_pdeg);
  int* pincl = (int*)(ws + o_pincl);
  int* pstart = (int*)(ws + o_pstart);
  int* pbsum = (int*)(ws + o_pbsum);
  int* pcsr = (int*)(ws + o_pcsr);
  float* agg = (float*)(ws + o_agg);
  float* xt1 = (float*)(ws + o_xt1);
  float* poolM = (float*)(ws + o_poolM);
  float* poolP = (float*)(ws + o_poolP);
  float* molv = (float*)(ws + o_molv);
  float* prov = (float*)(ws + o_prov);
  int* mbs = (int*)(ws + o_mbs);
  int* pbs = (int*)(ws + o_pbs);
  float* w1l = (float*)(ws + o_w1l);
  float* w1r = (float*)(ws + o_w1r);
  float* w2l = (float*)(ws + o_w2l);
  float* w2r = (float*)(ws + o_w2r);
  int* mbc = (int*)(ws + o_mbc);
  int* pbc = (int*)(ws + o_pbc);
  int2* mbinned = (int2*)hA;
  int2* pbinned = (int2*)agg;

  // weight transposes (tiny)
  k_trans<<<(DPK * DPK + 255) / 256, 256, 0, stream>>>(c1_Wl, w1l, DPK, DPK);
  k_trans<<<(DPK * DPK + 255) / 256, 256, 0, stream>>>(c1_Wr, w1r, DPK, DPK);
  k_trans<<<(DP2 * DPK + 255) / 256, 256, 0, stream>>>(c2_Wl, w2l, DP2, DPK);
  k_trans<<<(DP2 * DPK + 255) / 256, 256, 0, stream>>>(c2_Wr, w2r, DP2, DPK);

  // ===== MOL branch =====
  constexpr int SHM = 8;
  constexpr int NBM = (NM + (1 << SHM) - 1) >> SHM;
  hipMemsetAsync(mdeg, 0, (size_t)NM * 4, stream);
  k_count4<<<(EM / 4 + 255) / 256, 256, 0, stream>>>((const int4*)m_row, mdeg, EM / 4);
  int nb_m = (NM + 1023) / 1024;
  k_scan1<<<nb_m, 1024, 0, stream>>>(mdeg, mincl, mbsum, NM);
  k_scan2<<<1, 256, 0, stream>>>(mbsum, nb_m);
  k_scan3<<<(NM + 255) / 256, 256, 0, stream>>>(mincl, mdeg, mbsum, mstart, NM);
  k_bcur<SHM><<<(NBM + 255) / 256, 256, 0, stream>>>(mstart, mbc, NM);
  k_bin<SHM><<<(EM + 4095) / 4096, 256, 0, stream>>>(m_col, m_row, mbc, mbinned, EM);
  k_fill2<SHM><<<NBM, 256, 0, stream>>>(mbinned, mstart, mcsr, NM, EM);
  k_bstart<<<(NM + 255) / 256, 256, 0, stream>>>(m_batch, mbs, NM);

  int gb_m = (NM * 64 + 255) / 256;
  k_pool_seg<DM, 3, false><<<B, 256, 0, stream>>>(mol_x, mbs, poolM, 0.05f);
  k_gatherv<DM, false><<<gb_m, 256, 0, stream>>>(mol_x, mstart, mdeg, mcsr, hA, NM, DM);
  k_pool_seg<DM, 3, true><<<B, 256, 0, stream>>>(hA, mbs, poolM, 0.2375f);
  k_gatherv<DM, false><<<gb_m, 256, 0, stream>>>(hA, mstart, mdeg, mcsr, hB, NM, DM);
  k_pool_seg<DM, 3, true><<<B, 256, 0, stream>>>(hB, mbs, poolM, 0.2375f);
  k_gatherv<DM, false><<<gb_m, 256, 0, stream>>>(hB, mstart, mdeg, mcsr, hA, NM, DM);
  k_pool_seg<DM, 3, true><<<B, 256, 0, stream>>>(hA, mbs, poolM, 0.2375f);
  k_gatherv<DM, false><<<gb_m, 256, 0, stream>>>(hA, mstart, mdeg, mcsr, hB, NM, DM);
  k_pool_seg<DM, 3, true><<<B, 256, 0, stream>>>(hB, mbs, poolM, 0.2375f);
  k_head<DM, 112><<<B, 256, 0, stream>>>(poolM, mbs, mol_W1, mol_b1, mol_W2, mol_b2, molv);

  // ===== PRO branch =====
  constexpr int SHP = 9;
  constexpr int NBP = (NP + (1 << SHP) - 1) >> SHP;
  hipMemsetAsync(pdeg, 0, (size_t)NP * 4, stream);
  hipMemsetAsync(poolP, 0, (size_t)B * DP2 * 4, stream);
  k_count4<<<(EP / 4 + 255) / 256, 256, 0, stream>>>((const int4*)p_e1, pdeg, EP / 4);
  int nb_p = (NP + 1023) / 1024;
  k_scan1<<<nb_p, 1024, 0, stream>>>(pdeg, pincl, pbsum, NP);
  k_scan2<<<1, 256, 0, stream>>>(pbsum, nb_p);
  k_scan3<<<(NP + 255) / 256, 256, 0, stream>>>(pincl, pdeg, pbsum, pstart, NP);
  k_bcur<SHP><<<(NBP + 255) / 256, 256, 0, stream>>>(pstart, pbc, NP);
  k_bin<SHP><<<(EP + 4095) / 4096, 256, 0, stream>>>(p_e0, p_e1, pbc, pbinned, EP);
  k_fill2<SHP><<<NBP, 256, 0, stream>>>(pbinned, pstart, pcsr, NP, EP);
  k_bstart<<<(NP + 255) / 256, 256, 0, stream>>>(p_batch, pbs, NP);

  int gb_p = (NP * 64 + 255) / 256;
  k_gatherv<DPK, true><<<gb_p, 256, 0, stream>>>(pro_x, pstart, pdeg, pcsr, agg, NP, DPK);
  k_sage1_lds<<<(NP + 127) / 128, 256, 0, stream>>>(pro_x, agg, w1l, c1_bl, w1r, xt1, NP);
  k_gatherv<DPK, true><<<gb_p, 256, 0, stream>>>(xt1, pstart, pdeg, pcsr, agg, NP, DPK);
  k_sage2_lds<4><<<B * 4, 256, 0, stream>>>(xt1, agg, w2l, c2_bl, w2r, pbs, poolP);
  k_head<DP2, 144><<<B, 256, 0, stream>>>(poolP, pbs, pro_W1, pro_b1, pro_W2, pro_b2, prov);

  k_final<<<B, 256, 0, stream>>>(molv, prov, fc1_W, fc1_b, fc2_W, fc2_b, out_W, out_b, out);
}

// Round 8
// 1388.433 us; speedup vs baseline: 1.3839x; 1.0967x over previous
//
#include <hip/hip_runtime.h>

#define K256 __launch_bounds__(256)

constexpr int B = 128;
constexpr int NM = 100000, EM = 400000;
constexpr int NP = 200000, EP = 3200000;
constexpr int DM = 78, DPK = 54, DP2 = 108;
constexpr int XT = 56;  // padded row stride for xt1/agg (pads are exact zeros)

// ---------- CSR build ----------
__global__ void K256 k_count4(const int4* __restrict__ dst, int* __restrict__ deg, int E4) {
  int e = blockIdx.x * 256 + threadIdx.x;
  if (e < E4) {
    int4 v = dst[e];
    atomicAdd(&deg[v.x], 1);
    atomicAdd(&deg[v.y], 1);
    atomicAdd(&deg[v.z], 1);
    atomicAdd(&deg[v.w], 1);
  }
}

__global__ void k_scan1(const int* __restrict__ deg, int* __restrict__ incl,
                        int* __restrict__ bsum, int N) {
  __shared__ int s[1024];
  int i = blockIdx.x * 1024 + threadIdx.x;
  int v = (i < N) ? deg[i] : 0;
  s[threadIdx.x] = v;
  __syncthreads();
  for (int off = 1; off < 1024; off <<= 1) {
    int t = (threadIdx.x >= off) ? s[threadIdx.x - off] : 0;
    __syncthreads();
    s[threadIdx.x] += t;
    __syncthreads();
  }
  if (i < N) incl[i] = s[threadIdx.x];
  if (threadIdx.x == 1023) bsum[blockIdx.x] = s[1023];
}

__global__ void k_scan2(int* __restrict__ bsum, int nb) {
  __shared__ int s[256];
  int v = (threadIdx.x < (unsigned)nb) ? bsum[threadIdx.x] : 0;
  s[threadIdx.x] = v;
  __syncthreads();
  for (int off = 1; off < 256; off <<= 1) {
    int t = (threadIdx.x >= off) ? s[threadIdx.x - off] : 0;
    __syncthreads();
    s[threadIdx.x] += t;
    __syncthreads();
  }
  if (threadIdx.x < (unsigned)nb) bsum[threadIdx.x] = s[threadIdx.x] - v;  // exclusive
}

__global__ void K256 k_scan3(const int* __restrict__ incl, const int* __restrict__ deg,
                             const int* __restrict__ bsum, int* __restrict__ starts, int N) {
  int i = blockIdx.x * 256 + threadIdx.x;
  if (i < N) starts[i] = incl[i] - deg[i] + bsum[i >> 10];
}

template <int SH>
__global__ void K256 k_bcur(const int* __restrict__ starts, int* __restrict__ bcur, int N) {
  int b = blockIdx.x * 256 + threadIdx.x;
  int NB = (N + (1 << SH) - 1) >> SH;
  if (b < NB) bcur[b] = starts[b << SH];
}

// Pass A: bucket-grouped edge binning (counting-sort per 4096-edge chunk).
template <int SH>
__global__ void K256 k_bin(const int* __restrict__ src, const int* __restrict__ dst,
                           int* __restrict__ bcur, int2* __restrict__ binned, int E) {
  __shared__ int lh[512];
  __shared__ int gbase[512];
  int c0 = blockIdx.x * 4096;
  int tid = threadIdx.x;
  for (int t = tid; t < 512; t += 256) lh[t] = 0;
  __syncthreads();
  int r[16], dcache[16];
#pragma unroll
  for (int k = 0; k < 16; k++) {
    int e = c0 + k * 256 + tid;
    if (e < E) {
      int d = dst[e];
      dcache[k] = d;
      r[k] = atomicAdd(&lh[d >> SH], 1);
    }
  }
  __syncthreads();
  for (int b = tid; b < 512; b += 256) {
    int c = lh[b];
    gbase[b] = c ? atomicAdd(&bcur[b], c) : 0;
  }
  __syncthreads();
#pragma unroll
  for (int k = 0; k < 16; k++) {
    int e = c0 + k * 256 + tid;
    if (e < E) {
      int d = dcache[k];
      binned[gbase[d >> SH] + r[k]] = make_int2(src[e], d);
    }
  }
}

// Pass B: per-bucket CSR fill; node cursors in LDS.
template <int SH>
__global__ void K256 k_fill2(const int2* __restrict__ binned, const int* __restrict__ starts,
                             int* __restrict__ csr, int N, int E) {
  __shared__ int lcur[1 << SH];
  int b = blockIdx.x;
  int base = b << SH;
  int nn = min(N - base, 1 << SH);
  int tid = threadIdx.x;
  for (int t = tid; t < nn; t += 256) lcur[t] = starts[base + t];
  __syncthreads();
  int r0 = starts[base];
  int r1 = (base + (1 << SH) >= N) ? E : starts[base + (1 << SH)];
  for (int e = r0 + tid; e < r1; e += 256) {
    int2 sd = binned[e];
    int p = atomicAdd(&lcur[sd.y - base], 1);
    csr[p] = sd.x;
  }
}

// ---------- batch segment starts (batch is sorted) ----------
__global__ void K256 k_bstart(const int* __restrict__ batch, int* __restrict__ bstart, int N) {
  int i = blockIdx.x * 256 + threadIdx.x;
  if (i < N) {
    int b = batch[i];
    int pb = (i == 0) ? -1 : batch[i - 1];
    for (int bb = pb + 1; bb <= b; bb++) bstart[bb] = i;
    if (i == N - 1)
      for (int bb = b + 1; bb <= B; bb++) bstart[bb] = N;
  }
}

// ---------- weight prep: cat-form transposed weights ----------
// w1cat[k][o] (108 x 56): k<54 -> c1_Wl[o][k], k>=54 -> c1_Wr[o][k-54]; o>=54 pad 0
// w2cat[k][o] (108 x 108): k<54 -> c2_Wl[o][k], k>=54 -> c2_Wr[o][k-54]
__global__ void K256 k_prepw(const float* __restrict__ c1Wl, const float* __restrict__ c1Wr,
                             const float* __restrict__ c1bl, const float* __restrict__ c2Wl,
                             const float* __restrict__ c2Wr, float* __restrict__ w1cat,
                             float* __restrict__ bl1c, float* __restrict__ w2cat) {
  int i = blockIdx.x * 256 + threadIdx.x;
  if (i < 108 * 56) {
    int k = i / 56, o = i - k * 56;
    w1cat[i] = (o < 54) ? ((k < 54) ? c1Wl[o * 54 + k] : c1Wr[o * 54 + (k - 54)]) : 0.f;
  }
  if (i < 108 * 108) {
    int k = i / 108, o = i - k * 108;
    w2cat[i] = (k < 54) ? c2Wl[o * 54 + k] : c2Wr[o * 54 + (k - 54)];
  }
  if (i < 56) bl1c[i] = (i < 54) ? c1bl[i] : 0.f;
}

// ---------- gather aggregation: wave per node, float2 lanes, 2-deep edge ILP ----------
template <int D, bool MEAN>
__global__ void K256 k_gatherv(const float* __restrict__ x, const int* __restrict__ starts,
                               const int* __restrict__ deg, const int* __restrict__ csr,
                               float* __restrict__ out, int N, int ostride) {
  constexpr int NF2 = D / 2;
  int wid = (blockIdx.x * 256 + threadIdx.x) >> 6;
  int lane = threadIdx.x & 63;
  if (wid >= N) return;
  int s = starts[wid], d = deg[wid];
  const int* cp = csr + s;
  float ax = 0.f, ay = 0.f;
  if constexpr (NF2 <= 32) {
    int half = lane >> 5, sl = lane & 31;
    bool act = sl < NF2;
    float bx = 0.f, by = 0.f;
    int j = 0;
    for (; j + 4 <= d; j += 4) {
      if (act) {
        const float2* r0 = (const float2*)(x + (size_t)cp[j + half] * D);
        const float2* r1 = (const float2*)(x + (size_t)cp[j + 2 + half] * D);
        float2 v0 = r0[sl];
        float2 v1 = r1[sl];
        ax += v0.x;
        ay += v0.y;
        bx += v1.x;
        by += v1.y;
      }
    }
    for (; j < d; j += 2) {
      int e = j + half;
      if (e < d && act) {
        const float2* row = (const float2*)(x + (size_t)cp[e] * D);
        float2 v = row[sl];
        ax += v.x;
        ay += v.y;
      }
    }
    ax += bx;
    ay += by;
    ax += __shfl_xor(ax, 32, 64);
    ay += __shfl_xor(ay, 32, 64);
    if (half == 0 && act) {
      float inv = MEAN ? 1.f / fmaxf((float)d, 1.f) : 1.f;
      float2* op = (float2*)(out + (size_t)wid * ostride);
      float2 w;
      w.x = ax * inv;
      w.y = ay * inv;
      op[sl] = w;
    }
  } else {
    bool act = lane < NF2;
    float bx = 0.f, by = 0.f;
    int j = 0;
    for (; j + 2 <= d; j += 2) {
      if (act) {
        const float2* r0 = (const float2*)(x + (size_t)cp[j] * D);
        const float2* r1 = (const float2*)(x + (size_t)cp[j + 1] * D);
        float2 v0 = r0[lane];
        float2 v1 = r1[lane];
        ax += v0.x;
        ay += v0.y;
        bx += v1.x;
        by += v1.y;
      }
    }
    if (j < d && act) {
      const float2* row = (const float2*)(x + (size_t)cp[j] * D);
      float2 v = row[lane];
      ax += v.x;
      ay += v.y;
    }
    ax += bx;
    ay += by;
    if (act) {
      float inv = MEAN ? 1.f / fmaxf((float)d, 1.f) : 1.f;
      float2* op = (float2*)(out + (size_t)wid * ostride);
      float2 w;
      w.x = ax * inv;
      w.y = ay * inv;
      op[lane] = w;
    }
  }
}

// ---------- segmented pooling ----------
template <int D, int NPB, bool ACCUM>
__global__ void K256 k_pool_seg(const float* __restrict__ x, const int* __restrict__ bstart,
                                float* __restrict__ pooled, float coef) {
  __shared__ float sp[D * NPB];
  int b = blockIdx.x, tid = threadIdx.x;
  int r0 = bstart[b], r1 = bstart[b + 1];
  if (tid < D * NPB) {
    int ioff = tid / D, f = tid - ioff * D;
    float acc = 0.f;
    for (int i = r0 + ioff; i < r1; i += NPB) acc += x[(size_t)i * D + f];
    sp[tid] = acc;
  }
  __syncthreads();
  if (tid < D) {
    float s = 0.f;
#pragma unroll
    for (int g = 0; g < NPB; g++) s += sp[g * D + tid];
    s *= coef;
    if (ACCUM)
      pooled[b * D + tid] += s;
    else
      pooled[b * D + tid] = s;
  }
}

// ---------- SAGE conv1 cat-form: 64-node tile, 4 waves x 14 outputs ----------
__global__ void __launch_bounds__(256, 4) k_sage1c(
    const float* __restrict__ x,     // pro_x, stride 54
    const float* __restrict__ agg,   // stride XT (cols 0..53 valid)
    const float* __restrict__ wcat,  // [108][56]
    const float* __restrict__ blc,   // [56], pads 0
    float* __restrict__ out, int N) {  // stride XT; cols 54,55 get exact zeros
  __shared__ float scat[64 * 109];
  int base = blockIdx.x * 64;
  int nn = min(N - base, 64);
  int tid = threadIdx.x;
  for (int t = tid; t < nn * 27; t += 256) {
    int n = t / 27, j = t - n * 27;
    float2 va = *(const float2*)(agg + (size_t)(base + n) * XT + 2 * j);
    float2 vx = *(const float2*)(x + (size_t)(base + n) * 54 + 2 * j);
    float* sr = scat + n * 109;
    sr[2 * j] = va.x;
    sr[2 * j + 1] = va.y;
    sr[54 + 2 * j] = vx.x;
    sr[54 + 2 * j + 1] = vx.y;
  }
  __syncthreads();
  int w = tid >> 6, lane = tid & 63;
  int obase = __builtin_amdgcn_readfirstlane(w * 14);
  if (lane >= nn) return;
  float acc[14];
#pragma unroll
  for (int o = 0; o < 14; o++) acc[o] = blc[obase + o];
  const float* rs = scat + lane * 109;
#pragma unroll 2
  for (int k = 0; k < 108; k++) {
    float v = rs[k];
    const float* wr = wcat + k * 56 + obase;
#pragma unroll
    for (int o = 0; o < 14; o++) acc[o] += v * wr[o];
  }
  float* op = out + (size_t)(base + lane) * XT + obase;
#pragma unroll
  for (int o = 0; o < 14; o++) op[o] = fmaxf(acc[o], 0.f);
}

// ---------- conv2 + pool cat-form: 64-node tile, 4 waves x 27 outputs ----------
template <int SPLIT>
__global__ void __launch_bounds__(256, 4) k_sage2c(
    const float* __restrict__ xt1,   // stride XT
    const float* __restrict__ agg,   // stride XT
    const float* __restrict__ wcat,  // [108][108]
    const float* __restrict__ bl,    // [108]
    const int* __restrict__ bstart, float* __restrict__ pooled) {
  __shared__ float scat[64 * 109];
  int b = blockIdx.x / SPLIT;
  int sidx = blockIdx.x - b * SPLIT;
  int tid = threadIdx.x;
  int w = tid >> 6, lane = tid & 63;
  int obase = __builtin_amdgcn_readfirstlane(w * 27);
  int r0 = bstart[b], r1 = bstart[b + 1];
  int len = r1 - r0;
  int per = (len + SPLIT - 1) / SPLIT;
  int s0 = r0 + sidx * per;
  int s1 = min(r1, s0 + per);
  float pool[27];
#pragma unroll
  for (int o = 0; o < 27; o++) pool[o] = 0.f;
  for (int tb = s0; tb < s1; tb += 64) {
    int nn = min(s1 - tb, 64);
    __syncthreads();
    for (int t = tid; t < nn * 27; t += 256) {
      int n = t / 27, j = t - n * 27;
      float2 va = *(const float2*)(agg + (size_t)(tb + n) * XT + 2 * j);
      float2 vx = *(const float2*)(xt1 + (size_t)(tb + n) * XT + 2 * j);
      float* sr = scat + n * 109;
      sr[2 * j] = va.x;
      sr[2 * j + 1] = va.y;
      sr[54 + 2 * j] = vx.x;
      sr[54 + 2 * j + 1] = vx.y;
    }
    __syncthreads();
    if (lane < nn) {
      float acc[27];
#pragma unroll
      for (int o = 0; o < 27; o++) acc[o] = bl[obase + o];
      const float* rs = scat + lane * 109;
#pragma unroll 2
      for (int k = 0; k < 108; k++) {
        float v = rs[k];
        const float* wr = wcat + k * 108 + obase;
#pragma unroll
        for (int o = 0; o < 27; o++) acc[o] += v * wr[o];
      }
#pragma unroll
      for (int o = 0; o < 27; o++) pool[o] += fmaxf(acc[o], 0.f);
    }
  }
#pragma unroll
  for (int o = 0; o < 27; o++) {
#pragma unroll
    for (int off = 1; off < 64; off <<= 1) pool[o] += __shfl_xor(pool[o], off, 64);
  }
  if (lane == 0) {
    float* pb = pooled + b * DP2 + obase;
#pragma unroll
    for (int o = 0; o < 27; o++)
      if (pool[o] != 0.f) atomicAdd(&pb[o], pool[o]);
  }
}

// ---------- branch head MLP ----------
template <int DIN, int DOUT>
__global__ void K256 k_head(const float* __restrict__ pooled, const int* __restrict__ bstart,
                            const float* __restrict__ W1, const float* __restrict__ b1,
                            const float* __restrict__ W2, const float* __restrict__ b2,
                            float* __restrict__ outv) {
  __shared__ float sx[DIN];
  __shared__ float sh[256];
  int b = blockIdx.x, tid = threadIdx.x;
  float inv = 1.f / fmaxf((float)(bstart[b + 1] - bstart[b]), 1.f);
  for (int f = tid; f < DIN; f += 256) sx[f] = pooled[b * DIN + f] * inv;
  __syncthreads();
  float acc = b1[tid];
#pragma unroll 2
  for (int k = 0; k < DIN; k++) acc += sx[k] * W1[tid * DIN + k];
  sh[tid] = fmaxf(acc, 0.f);
  __syncthreads();
  if (tid < DOUT) {
    float a = b2[tid];
#pragma unroll 4
    for (int k = 0; k < 256; k++) a += sh[k] * W2[tid * 256 + k];
    outv[b * DOUT + tid] = a;
  }
}

// ---------- final MLP ----------
__global__ void K256 k_final(const float* __restrict__ molv, const float* __restrict__ prov,
                             const float* __restrict__ W1, const float* __restrict__ b1,
                             const float* __restrict__ W2, const float* __restrict__ b2,
                             const float* __restrict__ W3, const float* __restrict__ b3,
                             float* __restrict__ out) {
  __shared__ float sx[256];
  __shared__ float sh1[1024];
  __shared__ float sh2[512];
  __shared__ float red[4];
  int b = blockIdx.x, tid = threadIdx.x;
  sx[tid] = (tid < 112) ? molv[b * 112 + tid] : prov[b * 144 + (tid - 112)];
  __syncthreads();
  for (int o = tid; o < 1024; o += 256) {
    float a = b1[o];
#pragma unroll 4
    for (int k = 0; k < 256; k++) a += sx[k] * W1[o * 256 + k];
    sh1[o] = fmaxf(a, 0.f);
  }
  __syncthreads();
  for (int o = tid; o < 512; o += 256) {
    float a = b2[o];
#pragma unroll 4
    for (int k = 0; k < 1024; k++) a += sh1[k] * W2[o * 1024 + k];
    sh2[o] = fmaxf(a, 0.f);
  }
  __syncthreads();
  float a = 0.f;
  for (int k = tid; k < 512; k += 256) a += sh2[k] * W3[k];
  for (int off = 32; off > 0; off >>= 1) a += __shfl_down(a, off, 64);
  if ((tid & 63) == 0) red[tid >> 6] = a;
  __syncthreads();
  if (tid == 0) out[b] = red[0] + red[1] + red[2] + red[3] + b3[0];
}

__global__ void k_report(float* out, float v, int n) {
  int i = blockIdx.x * 256 + threadIdx.x;
  if (i < n) out[i] = v;
}

extern "C" void kernel_launch(void* const* d_in, const int* in_sizes, int n_in,
                              void* d_out, int out_size, void* d_ws, size_t ws_size,
                              hipStream_t stream) {
  (void)in_sizes; (void)n_in;
  const float* mol_x = (const float*)d_in[0];
  const int* m_ei = (const int*)d_in[1];
  const int* m_batch = (const int*)d_in[2];
  const float* pro_x = (const float*)d_in[3];
  const int* p_ei = (const int*)d_in[4];
  const int* p_batch = (const int*)d_in[5];
  const float* mol_W1 = (const float*)d_in[6];
  const float* mol_b1 = (const float*)d_in[7];
  const float* mol_W2 = (const float*)d_in[8];
  const float* mol_b2 = (const float*)d_in[9];
  const float* c1_Wl = (const float*)d_in[10];
  const float* c1_bl = (const float*)d_in[11];
  const float* c1_Wr = (const float*)d_in[12];
  const float* c2_Wl = (const float*)d_in[13];
  const float* c2_bl = (const float*)d_in[14];
  const float* c2_Wr = (const float*)d_in[15];
  const float* pro_W1 = (const float*)d_in[16];
  const float* pro_b1 = (const float*)d_in[17];
  const float* pro_W2 = (const float*)d_in[18];
  const float* pro_b2 = (const float*)d_in[19];
  const float* fc1_W = (const float*)d_in[20];
  const float* fc1_b = (const float*)d_in[21];
  const float* fc2_W = (const float*)d_in[22];
  const float* fc2_b = (const float*)d_in[23];
  const float* out_W = (const float*)d_in[24];
  const float* out_b = (const float*)d_in[25];
  float* out = (float*)d_out;
  char* ws = (char*)d_ws;

  const int* m_row = m_ei;       // dst
  const int* m_col = m_ei + EM;  // src
  const int* p_e0 = p_ei;        // src
  const int* p_e1 = p_ei + EP;   // dst

  auto al = [](size_t x) { return (x + 255) & ~(size_t)255; };

  size_t o = 0;
  size_t o_pdeg = o;   o += al((size_t)NP * 4);
  size_t o_pincl = o;  o += al((size_t)NP * 4);
  size_t o_pstart = o; o += al((size_t)NP * 4);
  size_t o_pbsum = o;  o += al(1024);
  size_t o_pcsr = o;   o += al((size_t)EP * 4);
  size_t o_agg = o;    o += al((size_t)NP * XT * 4);  // also pro binned (25.6MB <= 44.8MB)
  size_t o_xt1 = o;    o += al((size_t)NP * XT * 4);
  size_t pro_end = o;

  o = 0;
  size_t o_mdeg = o;   o += al((size_t)NM * 4);
  size_t o_mincl = o;  o += al((size_t)NM * 4);
  size_t o_mstart = o; o += al((size_t)NM * 4);
  size_t o_mbsum = o;  o += al(1024);
  size_t o_mcsr = o;   o += al((size_t)EM * 4);
  size_t o_hA = o;     o += al((size_t)NM * DM * 4);  // also mol binned
  size_t o_hB = o;     o += al((size_t)NM * DM * 4);
  size_t mol_end = o;

  size_t tail = al(pro_end > mol_end ? pro_end : mol_end);
  size_t o_poolM = tail; tail += al((size_t)B * DM * 4);
  size_t o_poolP = tail; tail += al((size_t)B * DP2 * 4);
  size_t o_molv = tail;  tail += al((size_t)B * 112 * 4);
  size_t o_prov = tail;  tail += al((size_t)B * 144 * 4);
  size_t o_mbs = tail;   tail += al((size_t)(B + 1) * 4);
  size_t o_pbs = tail;   tail += al((size_t)(B + 1) * 4);
  size_t o_w1c = tail;   tail += al((size_t)108 * 56 * 4);
  size_t o_bl1 = tail;   tail += al(56 * 4);
  size_t o_w2c = tail;   tail += al((size_t)108 * 108 * 4);
  size_t o_mbc = tail;   tail += al(512 * 4);
  size_t o_pbc = tail;   tail += al(512 * 4);

  if (ws_size < tail) {
    k_report<<<1, 256, 0, stream>>>(out, (float)(ws_size >> 20), out_size);
    return;
  }

  int* mdeg = (int*)(ws + o_mdeg);
  int* mincl = (int*)(ws + o_mincl);
  int* mstart = (int*)(ws + o_mstart);
  int* mbsum = (int*)(ws + o_mbsum);
  int* mcsr = (int*)(ws + o_mcsr);
  float* hA = (float*)(ws + o_hA);
  float* hB = (float*)(ws + o_hB);
  int* pdeg = (int*)(ws + o_pdeg);
  int* pincl = (int*)(ws + o_pincl);
  int* pstart = (int*)(ws + o_pstart);
  int* pbsum = (int*)(ws + o_pbsum);
  int* pcsr = (int*)(ws + o_pcsr);
  float* agg = (float*)(ws + o_agg);
  float* xt1 = (float*)(ws + o_xt1);
  float* poolM = (float*)(ws + o_poolM);
  float* poolP = (float*)(ws + o_poolP);
  float* molv = (float*)(ws + o_molv);
  float* prov = (float*)(ws + o_prov);
  int* mbs = (int*)(ws + o_mbs);
  int* pbs = (int*)(ws + o_pbs);
  float* w1cat = (float*)(ws + o_w1c);
  float* bl1c = (float*)(ws + o_bl1);
  float* w2cat = (float*)(ws + o_w2c);
  int* mbc = (int*)(ws + o_mbc);
  int* pbc = (int*)(ws + o_pbc);
  int2* mbinned = (int2*)hA;
  int2* pbinned = (int2*)agg;

  // weight prep (tiny)
  k_prepw<<<(108 * 108 + 255) / 256, 256, 0, stream>>>(c1_Wl, c1_Wr, c1_bl, c2_Wl, c2_Wr,
                                                       w1cat, bl1c, w2cat);

  // ===== MOL branch =====
  constexpr int SHM = 8;
  constexpr int NBM = (NM + (1 << SHM) - 1) >> SHM;
  hipMemsetAsync(mdeg, 0, (size_t)NM * 4, stream);
  k_count4<<<(EM / 4 + 255) / 256, 256, 0, stream>>>((const int4*)m_row, mdeg, EM / 4);
  int nb_m = (NM + 1023) / 1024;
  k_scan1<<<nb_m, 1024, 0, stream>>>(mdeg, mincl, mbsum, NM);
  k_scan2<<<1, 256, 0, stream>>>(mbsum, nb_m);
  k_scan3<<<(NM + 255) / 256, 256, 0, stream>>>(mincl, mdeg, mbsum, mstart, NM);
  k_bcur<SHM><<<(NBM + 255) / 256, 256, 0, stream>>>(mstart, mbc, NM);
  k_bin<SHM><<<(EM + 4095) / 4096, 256, 0, stream>>>(m_col, m_row, mbc, mbinned, EM);
  k_fill2<SHM><<<NBM, 256, 0, stream>>>(mbinned, mstart, mcsr, NM, EM);
  k_bstart<<<(NM + 255) / 256, 256, 0, stream>>>(m_batch, mbs, NM);

  int gb_m = (NM * 64 + 255) / 256;
  k_pool_seg<DM, 3, false><<<B, 256, 0, stream>>>(mol_x, mbs, poolM, 0.05f);
  k_gatherv<DM, false><<<gb_m, 256, 0, stream>>>(mol_x, mstart, mdeg, mcsr, hA, NM, DM);
  k_pool_seg<DM, 3, true><<<B, 256, 0, stream>>>(hA, mbs, poolM, 0.2375f);
  k_gatherv<DM, false><<<gb_m, 256, 0, stream>>>(hA, mstart, mdeg, mcsr, hB, NM, DM);
  k_pool_seg<DM, 3, true><<<B, 256, 0, stream>>>(hB, mbs, poolM, 0.2375f);
  k_gatherv<DM, false><<<gb_m, 256, 0, stream>>>(hB, mstart, mdeg, mcsr, hA, NM, DM);
  k_pool_seg<DM, 3, true><<<B, 256, 0, stream>>>(hA, mbs, poolM, 0.2375f);
  k_gatherv<DM, false><<<gb_m, 256, 0, stream>>>(hA, mstart, mdeg, mcsr, hB, NM, DM);
  k_pool_seg<DM, 3, true><<<B, 256, 0, stream>>>(hB, mbs, poolM, 0.2375f);
  k_head<DM, 112><<<B, 256, 0, stream>>>(poolM, mbs, mol_W1, mol_b1, mol_W2, mol_b2, molv);

  // ===== PRO branch =====
  constexpr int SHP = 9;
  constexpr int NBP = (NP + (1 << SHP) - 1) >> SHP;
  hipMemsetAsync(pdeg, 0, (size_t)NP * 4, stream);
  hipMemsetAsync(poolP, 0, (size_t)B * DP2 * 4, stream);
  k_count4<<<(EP / 4 + 255) / 256, 256, 0, stream>>>((const int4*)p_e1, pdeg, EP / 4);
  int nb_p = (NP + 1023) / 1024;
  k_scan1<<<nb_p, 1024, 0, stream>>>(pdeg, pincl, pbsum, NP);
  k_scan2<<<1, 256, 0, stream>>>(pbsum, nb_p);
  k_scan3<<<(NP + 255) / 256, 256, 0, stream>>>(pincl, pdeg, pbsum, pstart, NP);
  k_bcur<SHP><<<(NBP + 255) / 256, 256, 0, stream>>>(pstart, pbc, NP);
  k_bin<SHP><<<(EP + 4095) / 4096, 256, 0, stream>>>(p_e0, p_e1, pbc, pbinned, EP);
  k_fill2<SHP><<<NBP, 256, 0, stream>>>(pbinned, pstart, pcsr, NP, EP);
  k_bstart<<<(NP + 255) / 256, 256, 0, stream>>>(p_batch, pbs, NP);

  int gb_p = (NP * 64 + 255) / 256;
  // gather1: pro_x (stride 54) -> agg (stride 56, cols 0..53)
  k_gatherv<DPK, true><<<gb_p, 256, 0, stream>>>(pro_x, pstart, pdeg, pcsr, agg, NP, XT);
  // conv1: [agg|pro_x] @ w1cat -> xt1 (stride 56, pads exact zero)
  k_sage1c<<<(NP + 63) / 64, 256, 0, stream>>>(pro_x, agg, w1cat, bl1c, xt1, NP);
  // gather2: xt1 (stride 56, pads zero) -> agg (stride 56)
  k_gatherv<XT, true><<<gb_p, 256, 0, stream>>>(xt1, pstart, pdeg, pcsr, agg, NP, XT);
  // conv2 + pool
  k_sage2c<8><<<B * 8, 256, 0, stream>>>(xt1, agg, w2cat, c2_bl, pbs, poolP);
  k_head<DP2, 144><<<B, 256, 0, stream>>>(poolP, pbs, pro_W1, pro_b1, pro_W2, pro_b2, prov);

  k_final<<<B, 256, 0, stream>>>(molv, prov, fc1_W, fc1_b, fc2_W, fc2_b, out_W, out_b, out);
}

// Round 9
// 1327.472 us; speedup vs baseline: 1.4475x; 1.0459x over previous
//
#include <hip/hip_runtime.h>

#define K256 __launch_bounds__(256)

constexpr int B = 128;
constexpr int NM = 100000, EM = 400000;
constexpr int NP = 200000, EP = 3200000;
constexpr int DM = 78, DPK = 54, DP2 = 108;
constexpr int XH = 32;  // bf16 row stride in ushort2 units (64 bf16 = 128 B, line-aligned)

// ---- bf16 helpers (RTNE) ----
__device__ __forceinline__ float b2f(unsigned short u) {
  return __uint_as_float((unsigned int)u << 16);
}
__device__ __forceinline__ unsigned short f2b(float f) {
  unsigned int b = __float_as_uint(f);
  return (unsigned short)((b + 0x7fffu + ((b >> 16) & 1u)) >> 16);
}

// ---------- CSR build ----------
__global__ void K256 k_count4(const int4* __restrict__ dst, int* __restrict__ deg, int E4) {
  int e = blockIdx.x * 256 + threadIdx.x;
  if (e < E4) {
    int4 v = dst[e];
    atomicAdd(&deg[v.x], 1);
    atomicAdd(&deg[v.y], 1);
    atomicAdd(&deg[v.z], 1);
    atomicAdd(&deg[v.w], 1);
  }
}

__global__ void k_scan1(const int* __restrict__ deg, int* __restrict__ incl,
                        int* __restrict__ bsum, int N) {
  __shared__ int s[1024];
  int i = blockIdx.x * 1024 + threadIdx.x;
  int v = (i < N) ? deg[i] : 0;
  s[threadIdx.x] = v;
  __syncthreads();
  for (int off = 1; off < 1024; off <<= 1) {
    int t = (threadIdx.x >= off) ? s[threadIdx.x - off] : 0;
    __syncthreads();
    s[threadIdx.x] += t;
    __syncthreads();
  }
  if (i < N) incl[i] = s[threadIdx.x];
  if (threadIdx.x == 1023) bsum[blockIdx.x] = s[1023];
}

__global__ void k_scan2(int* __restrict__ bsum, int nb) {
  __shared__ int s[256];
  int v = (threadIdx.x < (unsigned)nb) ? bsum[threadIdx.x] : 0;
  s[threadIdx.x] = v;
  __syncthreads();
  for (int off = 1; off < 256; off <<= 1) {
    int t = (threadIdx.x >= off) ? s[threadIdx.x - off] : 0;
    __syncthreads();
    s[threadIdx.x] += t;
    __syncthreads();
  }
  if (threadIdx.x < (unsigned)nb) bsum[threadIdx.x] = s[threadIdx.x] - v;  // exclusive
}

__global__ void K256 k_scan3(const int* __restrict__ incl, const int* __restrict__ deg,
                             const int* __restrict__ bsum, int* __restrict__ starts, int N) {
  int i = blockIdx.x * 256 + threadIdx.x;
  if (i < N) starts[i] = incl[i] - deg[i] + bsum[i >> 10];
}

template <int SH>
__global__ void K256 k_bcur(const int* __restrict__ starts, int* __restrict__ bcur, int N) {
  int b = blockIdx.x * 256 + threadIdx.x;
  int NB = (N + (1 << SH) - 1) >> SH;
  if (b < NB) bcur[b] = starts[b << SH];
}

// Pass A: bucket-grouped edge binning (counting-sort per 4096-edge chunk).
template <int SH>
__global__ void K256 k_bin(const int* __restrict__ src, const int* __restrict__ dst,
                           int* __restrict__ bcur, int2* __restrict__ binned, int E) {
  __shared__ int lh[512];
  __shared__ int gbase[512];
  int c0 = blockIdx.x * 4096;
  int tid = threadIdx.x;
  for (int t = tid; t < 512; t += 256) lh[t] = 0;
  __syncthreads();
  int r[16], dcache[16];
#pragma unroll
  for (int k = 0; k < 16; k++) {
    int e = c0 + k * 256 + tid;
    if (e < E) {
      int d = dst[e];
      dcache[k] = d;
      r[k] = atomicAdd(&lh[d >> SH], 1);
    }
  }
  __syncthreads();
  for (int b = tid; b < 512; b += 256) {
    int c = lh[b];
    gbase[b] = c ? atomicAdd(&bcur[b], c) : 0;
  }
  __syncthreads();
#pragma unroll
  for (int k = 0; k < 16; k++) {
    int e = c0 + k * 256 + tid;
    if (e < E) {
      int d = dcache[k];
      binned[gbase[d >> SH] + r[k]] = make_int2(src[e], d);
    }
  }
}

// Pass B: per-bucket CSR fill; node cursors in LDS.
template <int SH>
__global__ void K256 k_fill2(const int2* __restrict__ binned, const int* __restrict__ starts,
                             int* __restrict__ csr, int N, int E) {
  __shared__ int lcur[1 << SH];
  int b = blockIdx.x;
  int base = b << SH;
  int nn = min(N - base, 1 << SH);
  int tid = threadIdx.x;
  for (int t = tid; t < nn; t += 256) lcur[t] = starts[base + t];
  __syncthreads();
  int r0 = starts[base];
  int r1 = (base + (1 << SH) >= N) ? E : starts[base + (1 << SH)];
  for (int e = r0 + tid; e < r1; e += 256) {
    int2 sd = binned[e];
    int p = atomicAdd(&lcur[sd.y - base], 1);
    csr[p] = sd.x;
  }
}

// ---------- batch segment starts (batch is sorted) ----------
__global__ void K256 k_bstart(const int* __restrict__ batch, int* __restrict__ bstart, int N) {
  int i = blockIdx.x * 256 + threadIdx.x;
  if (i < N) {
    int b = batch[i];
    int pb = (i == 0) ? -1 : batch[i - 1];
    for (int bb = pb + 1; bb <= b; bb++) bstart[bb] = i;
    if (i == N - 1)
      for (int bb = b + 1; bb <= B; bb++) bstart[bb] = N;
  }
}

// ---------- weight prep: cat-form transposed weights ----------
__global__ void K256 k_prepw(const float* __restrict__ c1Wl, const float* __restrict__ c1Wr,
                             const float* __restrict__ c1bl, const float* __restrict__ c2Wl,
                             const float* __restrict__ c2Wr, float* __restrict__ w1cat,
                             float* __restrict__ bl1c, float* __restrict__ w2cat) {
  int i = blockIdx.x * 256 + threadIdx.x;
  if (i < 108 * 56) {
    int k = i / 56, o = i - k * 56;
    w1cat[i] = (o < 54) ? ((k < 54) ? c1Wl[o * 54 + k] : c1Wr[o * 54 + (k - 54)]) : 0.f;
  }
  if (i < 108 * 108) {
    int k = i / 108, o = i - k * 108;
    w2cat[i] = (k < 54) ? c2Wl[o * 54 + k] : c2Wr[o * 54 + (k - 54)];
  }
  if (i < 56) bl1c[i] = (i < 54) ? c1bl[i] : 0.f;
}

// ---------- cast pro_x (f32 stride 54) -> bf16 rows (stride XH ushort2) ----------
__global__ void K256 k_cast(const float* __restrict__ x, ushort2* __restrict__ xh, int N) {
  int t = blockIdx.x * 256 + threadIdx.x;
  if (t < N * 27) {
    int n = t / 27, j = t - n * 27;
    float2 v = *(const float2*)(x + (size_t)n * 54 + 2 * j);
    xh[(size_t)n * XH + j] = make_ushort2(f2b(v.x), f2b(v.y));
  }
}

// ---------- bf16 gather: wave per node, 27 active lanes/half, 4-deep edge ILP ----------
__global__ void K256 k_gatherh(const ushort2* __restrict__ xh, const int* __restrict__ starts,
                               const int* __restrict__ deg, const int* __restrict__ csr,
                               ushort2* __restrict__ outh, int N) {
  int wid = (blockIdx.x * 256 + threadIdx.x) >> 6;
  int lane = threadIdx.x & 63;
  if (wid >= N) return;
  int s = starts[wid], d = deg[wid];
  const int* cp = csr + s;
  int half = lane >> 5, sl = lane & 31;
  bool act = sl < 27;
  float ax = 0.f, ay = 0.f, bx = 0.f, by = 0.f;
  int j = 0;
  for (; j + 4 <= d; j += 4) {
    if (act) {
      ushort2 v0 = xh[(size_t)cp[j + half] * XH + sl];
      ushort2 v1 = xh[(size_t)cp[j + 2 + half] * XH + sl];
      ax += b2f(v0.x);
      ay += b2f(v0.y);
      bx += b2f(v1.x);
      by += b2f(v1.y);
    }
  }
  for (; j < d; j += 2) {
    int e = j + half;
    if (e < d && act) {
      ushort2 v = xh[(size_t)cp[e] * XH + sl];
      ax += b2f(v.x);
      ay += b2f(v.y);
    }
  }
  ax += bx;
  ay += by;
  ax += __shfl_xor(ax, 32, 64);
  ay += __shfl_xor(ay, 32, 64);
  if (half == 0 && act) {
    float inv = 1.f / fmaxf((float)d, 1.f);
    outh[(size_t)wid * XH + sl] = make_ushort2(f2b(ax * inv), f2b(ay * inv));
  }
}

// ---------- f32 gather (mol): wave per node, float2 lanes, 2-deep edge ILP ----------
template <int D, bool MEAN>
__global__ void K256 k_gatherv(const float* __restrict__ x, const int* __restrict__ starts,
                               const int* __restrict__ deg, const int* __restrict__ csr,
                               float* __restrict__ out, int N, int ostride) {
  constexpr int NF2 = D / 2;
  int wid = (blockIdx.x * 256 + threadIdx.x) >> 6;
  int lane = threadIdx.x & 63;
  if (wid >= N) return;
  int s = starts[wid], d = deg[wid];
  const int* cp = csr + s;
  float ax = 0.f, ay = 0.f;
  bool act = lane < NF2;
  float bx = 0.f, by = 0.f;
  int j = 0;
  for (; j + 2 <= d; j += 2) {
    if (act) {
      const float2* r0 = (const float2*)(x + (size_t)cp[j] * D);
      const float2* r1 = (const float2*)(x + (size_t)cp[j + 1] * D);
      float2 v0 = r0[lane];
      float2 v1 = r1[lane];
      ax += v0.x;
      ay += v0.y;
      bx += v1.x;
      by += v1.y;
    }
  }
  if (j < d && act) {
    const float2* row = (const float2*)(x + (size_t)cp[j] * D);
    float2 v = row[lane];
    ax += v.x;
    ay += v.y;
  }
  ax += bx;
  ay += by;
  if (act) {
    float inv = MEAN ? 1.f / fmaxf((float)d, 1.f) : 1.f;
    float2* op = (float2*)(out + (size_t)wid * ostride);
    float2 w;
    w.x = ax * inv;
    w.y = ay * inv;
    op[lane] = w;
  }
}

// ---------- segmented pooling ----------
template <int D, int NPB, bool ACCUM>
__global__ void K256 k_pool_seg(const float* __restrict__ x, const int* __restrict__ bstart,
                                float* __restrict__ pooled, float coef) {
  __shared__ float sp[D * NPB];
  int b = blockIdx.x, tid = threadIdx.x;
  int r0 = bstart[b], r1 = bstart[b + 1];
  if (tid < D * NPB) {
    int ioff = tid / D, f = tid - ioff * D;
    float acc = 0.f;
    for (int i = r0 + ioff; i < r1; i += NPB) acc += x[(size_t)i * D + f];
    sp[tid] = acc;
  }
  __syncthreads();
  if (tid < D) {
    float s = 0.f;
#pragma unroll
    for (int g = 0; g < NPB; g++) s += sp[g * D + tid];
    s *= coef;
    if (ACCUM)
      pooled[b * D + tid] += s;
    else
      pooled[b * D + tid] = s;
  }
}

// ---------- SAGE conv1 cat-form: 64-node tile, 4 waves x 14 outputs; bf16 agg in, bf16 out ----------
__global__ void __launch_bounds__(256, 4) k_sage1c(
    const float* __restrict__ x,        // pro_x f32, stride 54
    const ushort2* __restrict__ aggh,   // bf16, stride XH
    const float* __restrict__ wcat,     // [108][56]
    const float* __restrict__ blc,      // [56], pads 0
    ushort2* __restrict__ outh, int N) {  // bf16, stride XH
  __shared__ float scat[64 * 109];
  int base = blockIdx.x * 64;
  int nn = min(N - base, 64);
  int tid = threadIdx.x;
  for (int t = tid; t < nn * 27; t += 256) {
    int n = t / 27, j = t - n * 27;
    ushort2 va = aggh[(size_t)(base + n) * XH + j];
    float2 vx = *(const float2*)(x + (size_t)(base + n) * 54 + 2 * j);
    float* sr = scat + n * 109;
    sr[2 * j] = b2f(va.x);
    sr[2 * j + 1] = b2f(va.y);
    sr[54 + 2 * j] = vx.x;
    sr[54 + 2 * j + 1] = vx.y;
  }
  __syncthreads();
  int w = tid >> 6, lane = tid & 63;
  int obase = __builtin_amdgcn_readfirstlane(w * 14);
  if (lane >= nn) return;
  float acc[14];
#pragma unroll
  for (int o = 0; o < 14; o++) acc[o] = blc[obase + o];
  const float* rs = scat + lane * 109;
#pragma unroll 2
  for (int k = 0; k < 108; k++) {
    float v = rs[k];
    const float* wr = wcat + k * 56 + obase;
#pragma unroll
    for (int o = 0; o < 14; o++) acc[o] += v * wr[o];
  }
  ushort2* op = outh + (size_t)(base + lane) * XH + (obase >> 1);
#pragma unroll
  for (int o = 0; o < 7; o++)
    op[o] = make_ushort2(f2b(fmaxf(acc[2 * o], 0.f)), f2b(fmaxf(acc[2 * o + 1], 0.f)));
}

// ---------- conv2 + pool cat-form: 64-node tile, 4 waves x 27 outputs; bf16 inputs ----------
template <int SPLIT>
__global__ void __launch_bounds__(256, 4) k_sage2c(
    const ushort2* __restrict__ xt1h,   // bf16, stride XH
    const ushort2* __restrict__ aggh,   // bf16, stride XH
    const float* __restrict__ wcat,     // [108][108]
    const float* __restrict__ bl,       // [108]
    const int* __restrict__ bstart, float* __restrict__ pooled) {
  __shared__ float scat[64 * 109];
  int b = blockIdx.x / SPLIT;
  int sidx = blockIdx.x - b * SPLIT;
  int tid = threadIdx.x;
  int w = tid >> 6, lane = tid & 63;
  int obase = __builtin_amdgcn_readfirstlane(w * 27);
  int r0 = bstart[b], r1 = bstart[b + 1];
  int len = r1 - r0;
  int per = (len + SPLIT - 1) / SPLIT;
  int s0 = r0 + sidx * per;
  int s1 = min(r1, s0 + per);
  float pool[27];
#pragma unroll
  for (int o = 0; o < 27; o++) pool[o] = 0.f;
  for (int tb = s0; tb < s1; tb += 64) {
    int nn = min(s1 - tb, 64);
    __syncthreads();
    for (int t = tid; t < nn * 27; t += 256) {
      int n = t / 27, j = t - n * 27;
      ushort2 va = aggh[(size_t)(tb + n) * XH + j];
      ushort2 vx = xt1h[(size_t)(tb + n) * XH + j];
      float* sr = scat + n * 109;
      sr[2 * j] = b2f(va.x);
      sr[2 * j + 1] = b2f(va.y);
      sr[54 + 2 * j] = b2f(vx.x);
      sr[54 + 2 * j + 1] = b2f(vx.y);
    }
    __syncthreads();
    if (lane < nn) {
      float acc[27];
#pragma unroll
      for (int o = 0; o < 27; o++) acc[o] = bl[obase + o];
      const float* rs = scat + lane * 109;
#pragma unroll 2
      for (int k = 0; k < 108; k++) {
        float v = rs[k];
        const float* wr = wcat + k * 108 + obase;
#pragma unroll
        for (int o = 0; o < 27; o++) acc[o] += v * wr[o];
      }
#pragma unroll
      for (int o = 0; o < 27; o++) pool[o] += fmaxf(acc[o], 0.f);
    }
  }
#pragma unroll
  for (int o = 0; o < 27; o++) {
#pragma unroll
    for (int off = 1; off < 64; off <<= 1) pool[o] += __shfl_xor(pool[o], off, 64);
  }
  if (lane == 0) {
    float* pb = pooled + b * DP2 + obase;
#pragma unroll
    for (int o = 0; o < 27; o++)
      if (pool[o] != 0.f) atomicAdd(&pb[o], pool[o]);
  }
}

// ---------- branch head MLP ----------
template <int DIN, int DOUT>
__global__ void K256 k_head(const float* __restrict__ pooled, const int* __restrict__ bstart,
                            const float* __restrict__ W1, const float* __restrict__ b1,
                            const float* __restrict__ W2, const float* __restrict__ b2,
                            float* __restrict__ outv) {
  __shared__ float sx[DIN];
  __shared__ float sh[256];
  int b = blockIdx.x, tid = threadIdx.x;
  float inv = 1.f / fmaxf((float)(bstart[b + 1] - bstart[b]), 1.f);
  for (int f = tid; f < DIN; f += 256) sx[f] = pooled[b * DIN + f] * inv;
  __syncthreads();
  float acc = b1[tid];
#pragma unroll 2
  for (int k = 0; k < DIN; k++) acc += sx[k] * W1[tid * DIN + k];
  sh[tid] = fmaxf(acc, 0.f);
  __syncthreads();
  if (tid < DOUT) {
    float a = b2[tid];
#pragma unroll 4
    for (int k = 0; k < 256; k++) a += sh[k] * W2[tid * 256 + k];
    outv[b * DOUT + tid] = a;
  }
}

// ---------- final MLP ----------
__global__ void K256 k_final(const float* __restrict__ molv, const float* __restrict__ prov,
                             const float* __restrict__ W1, const float* __restrict__ b1,
                             const float* __restrict__ W2, const float* __restrict__ b2,
                             const float* __restrict__ W3, const float* __restrict__ b3,
                             float* __restrict__ out) {
  __shared__ float sx[256];
  __shared__ float sh1[1024];
  __shared__ float sh2[512];
  __shared__ float red[4];
  int b = blockIdx.x, tid = threadIdx.x;
  sx[tid] = (tid < 112) ? molv[b * 112 + tid] : prov[b * 144 + (tid - 112)];
  __syncthreads();
  for (int o = tid; o < 1024; o += 256) {
    float a = b1[o];
#pragma unroll 4
    for (int k = 0; k < 256; k++) a += sx[k] * W1[o * 256 + k];
    sh1[o] = fmaxf(a, 0.f);
  }
  __syncthreads();
  for (int o = tid; o < 512; o += 256) {
    float a = b2[o];
#pragma unroll 4
    for (int k = 0; k < 1024; k++) a += sh1[k] * W2[o * 1024 + k];
    sh2[o] = fmaxf(a, 0.f);
  }
  __syncthreads();
  float a = 0.f;
  for (int k = tid; k < 512; k += 256) a += sh2[k] * W3[k];
  for (int off = 32; off > 0; off >>= 1) a += __shfl_down(a, off, 64);
  if ((tid & 63) == 0) red[tid >> 6] = a;
  __syncthreads();
  if (tid == 0) out[b] = red[0] + red[1] + red[2] + red[3] + b3[0];
}

__global__ void k_report(float* out, float v, int n) {
  int i = blockIdx.x * 256 + threadIdx.x;
  if (i < n) out[i] = v;
}

extern "C" void kernel_launch(void* const* d_in, const int* in_sizes, int n_in,
                              void* d_out, int out_size, void* d_ws, size_t ws_size,
                              hipStream_t stream) {
  (void)in_sizes; (void)n_in;
  const float* mol_x = (const float*)d_in[0];
  const int* m_ei = (const int*)d_in[1];
  const int* m_batch = (const int*)d_in[2];
  const float* pro_x = (const float*)d_in[3];
  const int* p_ei = (const int*)d_in[4];
  const int* p_batch = (const int*)d_in[5];
  const float* mol_W1 = (const float*)d_in[6];
  const float* mol_b1 = (const float*)d_in[7];
  const float* mol_W2 = (const float*)d_in[8];
  const float* mol_b2 = (const float*)d_in[9];
  const float* c1_Wl = (const float*)d_in[10];
  const float* c1_bl = (const float*)d_in[11];
  const float* c1_Wr = (const float*)d_in[12];
  const float* c2_Wl = (const float*)d_in[13];
  const float* c2_bl = (const float*)d_in[14];
  const float* c2_Wr = (const float*)d_in[15];
  const float* pro_W1 = (const float*)d_in[16];
  const float* pro_b1 = (const float*)d_in[17];
  const float* pro_W2 = (const float*)d_in[18];
  const float* pro_b2 = (const float*)d_in[19];
  const float* fc1_W = (const float*)d_in[20];
  const float* fc1_b = (const float*)d_in[21];
  const float* fc2_W = (const float*)d_in[22];
  const float* fc2_b = (const float*)d_in[23];
  const float* out_W = (const float*)d_in[24];
  const float* out_b = (const float*)d_in[25];
  float* out = (float*)d_out;
  char* ws = (char*)d_ws;

  const int* m_row = m_ei;       // dst
  const int* m_col = m_ei + EM;  // src
  const int* p_e0 = p_ei;        // src
  const int* p_e1 = p_ei + EP;   // dst

  auto al = [](size_t x) { return (x + 255) & ~(size_t)255; };

  size_t o = 0;
  size_t o_pdeg = o;   o += al((size_t)NP * 4);
  size_t o_pincl = o;  o += al((size_t)NP * 4);
  size_t o_pstart = o; o += al((size_t)NP * 4);
  size_t o_pbsum = o;  o += al(1024);
  size_t o_pcsr = o;   o += al((size_t)EP * 4);
  size_t o_aggh = o;   o += al((size_t)NP * XH * 4);  // bf16 rows; also pro binned (both 25.6MB)
  size_t o_xt1h = o;   o += al((size_t)NP * XH * 4);
  size_t o_pxh = o;    o += al((size_t)NP * XH * 4);
  size_t pro_end = o;

  o = 0;
  size_t o_mdeg = o;   o += al((size_t)NM * 4);
  size_t o_mincl = o;  o += al((size_t)NM * 4);
  size_t o_mstart = o; o += al((size_t)NM * 4);
  size_t o_mbsum = o;  o += al(1024);
  size_t o_mcsr = o;   o += al((size_t)EM * 4);
  size_t o_hA = o;     o += al((size_t)NM * DM * 4);  // also mol binned
  size_t o_hB = o;     o += al((size_t)NM * DM * 4);
  size_t mol_end = o;

  size_t tail = al(pro_end > mol_end ? pro_end : mol_end);
  size_t o_poolM = tail; tail += al((size_t)B * DM * 4);
  size_t o_poolP = tail; tail += al((size_t)B * DP2 * 4);
  size_t o_molv = tail;  tail += al((size_t)B * 112 * 4);
  size_t o_prov = tail;  tail += al((size_t)B * 144 * 4);
  size_t o_mbs = tail;   tail += al((size_t)(B + 1) * 4);
  size_t o_pbs = tail;   tail += al((size_t)(B + 1) * 4);
  size_t o_w1c = tail;   tail += al((size_t)108 * 56 * 4);
  size_t o_bl1 = tail;   tail += al(56 * 4);
  size_t o_w2c = tail;   tail += al((size_t)108 * 108 * 4);
  size_t o_mbc = tail;   tail += al(512 * 4);
  size_t o_pbc = tail;   tail += al(512 * 4);

  if (ws_size < tail) {
    k_report<<<1, 256, 0, stream>>>(out, (float)(ws_size >> 20), out_size);
    return;
  }

  int* mdeg = (int*)(ws + o_mdeg);
  int* mincl = (int*)(ws + o_mincl);
  int* mstart = (int*)(ws + o_mstart);
  int* mbsum = (int*)(ws + o_mbsum);
  int* mcsr = (int*)(ws + o_mcsr);
  float* hA = (float*)(ws + o_hA);
  float* hB = (float*)(ws + o_hB);
  int* pdeg = (int*)(ws + o_pdeg);
  int* pincl = (int*)(ws + o_pincl);
  int* pstart = (int*)(ws + o_pstart);
  int* pbsum = (int*)(ws + o_pbsum);
  int* pcsr = (int*)(ws + o_pcsr);
  ushort2* aggh = (ushort2*)(ws + o_aggh);
  ushort2* xt1h = (ushort2*)(ws + o_xt1h);
  ushort2* pxh = (ushort2*)(ws + o_pxh);
  float* poolM = (float*)(ws + o_poolM);
  float* poolP = (float*)(ws + o_poolP);
  float* molv = (float*)(ws + o_molv);
  float* prov = (float*)(ws + o_prov);
  int* mbs = (int*)(ws + o_mbs);
  int* pbs = (int*)(ws + o_pbs);
  float* w1cat = (float*)(ws + o_w1c);
  float* bl1c = (float*)(ws + o_bl1);
  float* w2cat = (float*)(ws + o_w2c);
  int* mbc = (int*)(ws + o_mbc);
  int* pbc = (int*)(ws + o_pbc);
  int2* mbinned = (int2*)hA;
  int2* pbinned = (int2*)aggh;  // consumed by fill2 before aggh is written

  // weight prep (tiny)
  k_prepw<<<(108 * 108 + 255) / 256, 256, 0, stream>>>(c1_Wl, c1_Wr, c1_bl, c2_Wl, c2_Wr,
                                                       w1cat, bl1c, w2cat);

  // ===== MOL branch (f32 — APPNP amplifies magnitudes; keep exact) =====
  constexpr int SHM = 8;
  constexpr int NBM = (NM + (1 << SHM) - 1) >> SHM;
  hipMemsetAsync(mdeg, 0, (size_t)NM * 4, stream);
  k_count4<<<(EM / 4 + 255) / 256, 256, 0, stream>>>((const int4*)m_row, mdeg, EM / 4);
  int nb_m = (NM + 1023) / 1024;
  k_scan1<<<nb_m, 1024, 0, stream>>>(mdeg, mincl, mbsum, NM);
  k_scan2<<<1, 256, 0, stream>>>(mbsum, nb_m);
  k_scan3<<<(NM + 255) / 256, 256, 0, stream>>>(mincl, mdeg, mbsum, mstart, NM);
  k_bcur<SHM><<<(NBM + 255) / 256, 256, 0, stream>>>(mstart, mbc, NM);
  k_bin<SHM><<<(EM + 4095) / 4096, 256, 0, stream>>>(m_col, m_row, mbc, mbinned, EM);
  k_fill2<SHM><<<NBM, 256, 0, stream>>>(mbinned, mstart, mcsr, NM, EM);
  k_bstart<<<(NM + 255) / 256, 256, 0, stream>>>(m_batch, mbs, NM);

  int gb_m = (NM * 64 + 255) / 256;
  k_pool_seg<DM, 3, false><<<B, 256, 0, stream>>>(mol_x, mbs, poolM, 0.05f);
  k_gatherv<DM, false><<<gb_m, 256, 0, stream>>>(mol_x, mstart, mdeg, mcsr, hA, NM, DM);
  k_pool_seg<DM, 3, true><<<B, 256, 0, stream>>>(hA, mbs, poolM, 0.2375f);
  k_gatherv<DM, false><<<gb_m, 256, 0, stream>>>(hA, mstart, mdeg, mcsr, hB, NM, DM);
  k_pool_seg<DM, 3, true><<<B, 256, 0, stream>>>(hB, mbs, poolM, 0.2375f);
  k_gatherv<DM, false><<<gb_m, 256, 0, stream>>>(hB, mstart, mdeg, mcsr, hA, NM, DM);
  k_pool_seg<DM, 3, true><<<B, 256, 0, stream>>>(hA, mbs, poolM, 0.2375f);
  k_gatherv<DM, false><<<gb_m, 256, 0, stream>>>(hA, mstart, mdeg, mcsr, hB, NM, DM);
  k_pool_seg<DM, 3, true><<<B, 256, 0, stream>>>(hB, mbs, poolM, 0.2375f);
  k_head<DM, 112><<<B, 256, 0, stream>>>(poolM, mbs, mol_W1, mol_b1, mol_W2, mol_b2, molv);

  // ===== PRO branch (bf16 feature rows, 128B-aligned; mean-aggr keeps noise bounded) =====
  constexpr int SHP = 9;
  constexpr int NBP = (NP + (1 << SHP) - 1) >> SHP;
  hipMemsetAsync(pdeg, 0, (size_t)NP * 4, stream);
  hipMemsetAsync(poolP, 0, (size_t)B * DP2 * 4, stream);
  k_count4<<<(EP / 4 + 255) / 256, 256, 0, stream>>>((const int4*)p_e1, pdeg, EP / 4);
  int nb_p = (NP + 1023) / 1024;
  k_scan1<<<nb_p, 1024, 0, stream>>>(pdeg, pincl, pbsum, NP);
  k_scan2<<<1, 256, 0, stream>>>(pbsum, nb_p);
  k_scan3<<<(NP + 255) / 256, 256, 0, stream>>>(pincl, pdeg, pbsum, pstart, NP);
  k_bcur<SHP><<<(NBP + 255) / 256, 256, 0, stream>>>(pstart, pbc, NP);
  k_bin<SHP><<<(EP + 4095) / 4096, 256, 0, stream>>>(p_e0, p_e1, pbc, pbinned, EP);
  k_fill2<SHP><<<NBP, 256, 0, stream>>>(pbinned, pstart, pcsr, NP, EP);
  k_bstart<<<(NP + 255) / 256, 256, 0, stream>>>(p_batch, pbs, NP);
  k_cast<<<(NP * 27 + 255) / 256, 256, 0, stream>>>(pro_x, pxh, NP);

  int gb_p = (NP * 64 + 255) / 256;
  // gather1: pxh (bf16) -> aggh (bf16)
  k_gatherh<<<gb_p, 256, 0, stream>>>(pxh, pstart, pdeg, pcsr, aggh, NP);
  // conv1: [aggh|pro_x] @ w1cat -> xt1h (bf16)
  k_sage1c<<<(NP + 63) / 64, 256, 0, stream>>>(pro_x, aggh, w1cat, bl1c, xt1h, NP);
  // gather2: xt1h -> aggh
  k_gatherh<<<gb_p, 256, 0, stream>>>(xt1h, pstart, pdeg, pcsr, aggh, NP);
  // conv2 + pool
  k_sage2c<8><<<B * 8, 256, 0, stream>>>(xt1h, aggh, w2cat, c2_bl, pbs, poolP);
  k_head<DP2, 144><<<B, 256, 0, stream>>>(poolP, pbs, pro_W1, pro_b1, pro_W2, pro_b2, prov);

  k_final<<<B, 256, 0, stream>>>(molv, prov, fc1_W, fc1_b, fc2_W, fc2_b, out_W, out_b, out);
}